// Round 8
// baseline (359.966 us; speedup 1.0000x reference)
//
#include <hip/hip_runtime.h>
#include <stdint.h>

// ---------------- problem constants ----------------
#define N_ROWS 4096      // bs*seq = 8*512
#define DDIM   512
#define KCODES 8192
#define NK     (N_ROWS * KCODES)   // 33,554,432
#define HALF_NK 16777216u
#define BS_F   8.0f
#define INV_N  (1.0f / 4096.0f)

// ---------------- ws layout (float offsets) ----------------
// logit region (NK floats): row n's 32KB slot holds (after k_fused)
//   [0,16KB):  bf16 encodings for row n  (read by k_mid gemm2-role)
//   [16KB,32KB): for slots n<2048: colsum partial fragment (read by k_mid tail1-role)
// part[b][c] (b<1024): c<4096 -> slot 2b second half; c>=4096 -> slot 2b+1.
// zh region (dead after gemm1) hosts S[16][8192] second-level colsums (512KB).
// cbl (8MB) reused as outA (gemm2 k-split partial 0) after gemm1.
#define OFF_LOGIT   0
#define OFF_CNORM   (NK)
#define OFF_ACC     (OFF_CNORM + KCODES)   // [0]=sum p*logp, [1]=sum (z-zhat)^2, [2]=entropy
#define OFF_ZH      (OFF_ACC + 4)                    // bf16 z hi  [4096*512]
#define OFF_ZL      (OFF_ZH + (N_ROWS*DDIM/2))       // bf16 z lo
#define OFF_CBH     (OFF_ZL + (N_ROWS*DDIM/2))       // bf16 cb hi [8192*512]
#define OFF_CBL     (OFF_CBH + (KCODES*DDIM/2))      // bf16 cb lo
#define OFF_CBT     (OFF_CBL + (KCODES*DDIM/2))      // bf16 cb^T  [512*8192]
#define WS_FLOATS   (OFF_CBT + (DDIM*KCODES/2))      // ~168MB

typedef __attribute__((ext_vector_type(8))) short short8;
typedef __attribute__((ext_vector_type(4))) float f32x4;

__device__ __forceinline__ unsigned short f2bf(float x) {
    uint32_t u = __float_as_uint(x);
    u += 0x7fffu + ((u >> 16) & 1u);
    return (unsigned short)(u >> 16);
}

// async global->LDS, 16B per lane; lds base must be wave-uniform,
// lane i lands at lds + i*16 (no padding allowed in the chunk).
__device__ __forceinline__ void cp16(const unsigned short* g, unsigned short* l) {
    __builtin_amdgcn_global_load_lds(
        (const __attribute__((address_space(1))) void*)g,
        (__attribute__((address_space(3))) void*)l, 16, 0, 0);
}

// ---------------- JAX threefry2x32-20, key(42) = (0,42) ----------------
__device__ __forceinline__ uint32_t rotl32(uint32_t x, int r) {
    return (x << r) | (x >> (32 - r));
}

__device__ __forceinline__ void threefry2(uint32_t c0, uint32_t c1,
                                          uint32_t& o0, uint32_t& o1) {
    const uint32_t ks0 = 0u, ks1 = 42u, ks2 = 0x1BD11BDAu ^ 0u ^ 42u;
    uint32_t x0 = c0 + ks0;
    uint32_t x1 = c1 + ks1;
#define TF_R(r) { x0 += x1; x1 = rotl32(x1, r); x1 ^= x0; }
    TF_R(13) TF_R(15) TF_R(26) TF_R(6)
    x0 += ks1; x1 += ks2 + 1u;
    TF_R(17) TF_R(29) TF_R(16) TF_R(24)
    x0 += ks2; x1 += ks0 + 2u;
    TF_R(13) TF_R(15) TF_R(26) TF_R(6)
    x0 += ks0; x1 += ks1 + 3u;
    TF_R(17) TF_R(29) TF_R(16) TF_R(24)
    x0 += ks1; x1 += ks2 + 4u;
    TF_R(13) TF_R(15) TF_R(26) TF_R(6)
    x0 += ks2; x1 += ks0 + 5u;
#undef TF_R
    o0 = x0; o1 = x1;
}

__device__ __forceinline__ float u01(uint32_t bits) {
    return __uint_as_float((bits >> 9) | 0x3f800000u) - 1.0f;
}

__device__ __forceinline__ float gum(uint32_t bits) {
    float u = u01(bits);
    return -__logf(-__logf(u + 1e-10f) + 1e-10f);
}

// ---------------- block reduce helpers (256 threads = 4 waves) ----------------
__device__ __forceinline__ float blockReduce1(float v, float* red) {
    #pragma unroll
    for (int o = 32; o > 0; o >>= 1) v += __shfl_down(v, o);
    __syncthreads();
    if ((threadIdx.x & 63) == 0) red[threadIdx.x >> 6] = v;
    __syncthreads();
    return red[0] + red[1] + red[2] + red[3];
}

__device__ __forceinline__ void red2max(float& a, float& b, float* red) {
    #pragma unroll
    for (int o = 32; o > 0; o >>= 1) {
        a = fmaxf(a, __shfl_down(a, o));
        b = fmaxf(b, __shfl_down(b, o));
    }
    __syncthreads();
    if ((threadIdx.x & 63) == 0) {
        red[(threadIdx.x >> 6) * 2 + 0] = a;
        red[(threadIdx.x >> 6) * 2 + 1] = b;
    }
    __syncthreads();
    a = fmaxf(fmaxf(red[0], red[2]), fmaxf(red[4], red[6]));
    b = fmaxf(fmaxf(red[1], red[3]), fmaxf(red[5], red[7]));
}

__device__ __forceinline__ void red3sum(float& a, float& b, float& c, float* red) {
    #pragma unroll
    for (int o = 32; o > 0; o >>= 1) {
        a += __shfl_down(a, o);
        b += __shfl_down(b, o);
        c += __shfl_down(c, o);
    }
    __syncthreads();
    if ((threadIdx.x & 63) == 0) {
        red[(threadIdx.x >> 6) * 3 + 0] = a;
        red[(threadIdx.x >> 6) * 3 + 1] = b;
        red[(threadIdx.x >> 6) * 3 + 2] = c;
    }
    __syncthreads();
    a = red[0] + red[3] + red[6] + red[9];
    b = red[1] + red[4] + red[7] + red[10];
    c = red[2] + red[5] + red[8] + red[11];
}

// ---------------- K1: fused prep ----------------
__global__ __launch_bounds__(256) void k_prep(const float* __restrict__ z,
                                              const float* __restrict__ cb,
                                              unsigned short* __restrict__ zh,
                                              unsigned short* __restrict__ zl,
                                              unsigned short* __restrict__ cbh,
                                              unsigned short* __restrict__ cbl,
                                              unsigned short* __restrict__ cbT,
                                              float* __restrict__ cnorm,
                                              float* __restrict__ accp) {
    __shared__ unsigned short TT[64][65];
    const int b = blockIdx.x;
    const int t = threadIdx.x;
    if (b < 3072) {
        const bool isz = (b < 1024);
        const int bb = isz ? b : b - 1024;
        const float* src = isz ? z : cb;
        unsigned short* hi = isz ? zh : cbh;
        unsigned short* lo = isz ? zl : cbl;
        const size_t idx = ((size_t)bb * 256 + t) * 8;
        float4 a = *(const float4*)(src + idx);
        float4 bv = *(const float4*)(src + idx + 4);
        float f[8] = {a.x, a.y, a.z, a.w, bv.x, bv.y, bv.z, bv.w};
        unsigned short h8[8], l8[8];
        float s = 0.f;
        #pragma unroll
        for (int e = 0; e < 8; ++e) {
            unsigned short h = f2bf(f[e]);
            float hf = __uint_as_float((uint32_t)h << 16);
            h8[e] = h;
            l8[e] = f2bf(f[e] - hf);
            s += f[e] * f[e];
        }
        *(short8*)(hi + idx) = *(short8*)h8;
        *(short8*)(lo + idx) = *(short8*)l8;
        if (!isz) {
            #pragma unroll
            for (int o = 32; o > 0; o >>= 1) s += __shfl_down(s, o);
            if ((t & 63) == 0) cnorm[bb * 4 + (t >> 6)] = s;
        }
    } else if (b < 4096) {
        const int b3 = b - 3072;
        const int k0 = (b3 & 127) * 64;
        const int d0 = (b3 >> 7) * 64;
        #pragma unroll
        for (int j = 0; j < 4; ++j) {
            const int unit = t + j * 256;
            const int r = unit >> 4;
            const int s4 = unit & 15;
            float4 v = *(const float4*)(cb + (size_t)(k0 + r) * DDIM + d0 + s4 * 4);
            TT[r][s4*4+0] = f2bf(v.x); TT[r][s4*4+1] = f2bf(v.y);
            TT[r][s4*4+2] = f2bf(v.z); TT[r][s4*4+3] = f2bf(v.w);
        }
        __syncthreads();
        #pragma unroll
        for (int j = 0; j < 2; ++j) {
            const int unit = t + j * 256;
            const int dr = unit >> 3;
            const int ks = (unit & 7) * 8;
            unsigned short o8[8];
            #pragma unroll
            for (int i = 0; i < 8; ++i) o8[i] = TT[ks + i][dr];
            *(short8*)(cbT + (size_t)(d0 + dr) * KCODES + k0 + ks) = *(short8*)o8;
        }
    } else {
        if (t < 4) accp[t] = 0.f;
    }
}

// ---------------- K2: GEMM1 — 256x256, 8 waves, 8-phase fine interleave -----
// R8: reinstate R1's quadrant-phase schedule (24 MFMA/phase, reads issued
// BEFORE the entry barrier, two raw barriers per phase, counted vmcnt(4)
// twice per iteration, never 0 in the loop) — the m196/m201-proven fine
// interleave — now with the two memory fixes R1 lacked:
//   (1) n-slab XCD map (R2): FETCH 163->55MB, B L2-resident.
//   (2) row-XOR both-sides swizzle (R2/R3): bank conflicts 12.6M->0.
// Peeled-iteration fix vs R1: VM0 at peeled-p3 (R1's p5 B-delta read relied
// on an un-waited load; latent race made airtight, costs nothing at tail).
__global__ __launch_bounds__(512, 2)
void k_gemm1(const unsigned short* __restrict__ zh,
             const unsigned short* __restrict__ zl,
             const unsigned short* __restrict__ cbh,
             const unsigned short* __restrict__ cbl,
             const float* __restrict__ cnorm,
             const float* __restrict__ var_q,
             float* __restrict__ logit) {
    __shared__ __align__(1024) unsigned short As[2][256 * 64];   // 2 x 32KB
    __shared__ __align__(1024) unsigned short Bs[2][256 * 64];   // 2 x 32KB

    const int t    = threadIdx.x;           // 0..511
    const int wid  = t >> 6;                // 0..7
    const int lane = t & 63;
    const int lrow = lane & 15;
    const int lq   = lane >> 4;
    const int wm   = (wid >> 2) * 128;      // 2 M-waves
    const int wn   = (wid & 3) * 64;        // 4 N-waves

    // XCD n-slab mapping: x = bid&7 -> n-tiles [4x,4x+4); local covers 16m x 4n
    const int bid   = blockIdx.x;
    const int x     = bid & 7;
    const int local = bid >> 3;
    const int m_t   = (local & 7) | ((local >> 5) << 3);
    const int n_t   = x * 4 + ((local >> 3) & 3);
    const int m0 = m_t * 256;
    const int n0 = n_t * 256;

    // staging source swizzle: lane writes phys slot (lane&7) of row (+lane>>3);
    // logical slot = (lane&7) ^ (lane>>3): <4 -> hi kquad, >=4 -> lo kquad.
    const int sl = (lane & 7) ^ (lane >> 3);
    const unsigned short* asrc = (sl < 4 ? zh : zl) + (sl & 3) * 8;
    const unsigned short* bsrc = (sl < 4 ? cbh : cbl) + (sl & 3) * 8;
    const int rA = (wid << 3) + (lane >> 3);                        // A row offset
    const int rB = ((wid & 3) << 3) + ((wid >> 2) << 6) + (lane >> 3); // B row offset

#define STG_A(bf, ab, kt)                                                     \
    cp16(asrc + (size_t)(m0 + (ab) + rA) * 512 + (kt) * 32,                   \
         &As[bf][((ab) + (wid << 3)) * 64])
#define STG_B(bf, bb_, kt)                                                    \
    cp16(bsrc + (size_t)(n0 + (bb_) + rB) * 512 + (kt) * 32,                  \
         &Bs[bf][((bb_) + ((wid & 3) << 3) + ((wid >> 2) << 6)) * 64])

    f32x4 acc[8][4];
    #pragma unroll
    for (int i = 0; i < 8; ++i)
        #pragma unroll
        for (int jj = 0; jj < 4; ++jj)
            acc[i][jj] = (f32x4){0.f, 0.f, 0.f, 0.f};

#define VM_NONE
#define VM4 asm volatile("s_waitcnt vmcnt(4)" ::: "memory");
#define VM0 asm volatile("s_waitcnt vmcnt(0)" ::: "memory");

// Phase (bf, mh, nh): read A-quadrant (4 rows hi+lo) + B-quadrant (2 rows
// hi+lo) BEFORE the entry barrier (data staged >=2 phases ago, landed via a
// prior counted vmcnt + barrier); issue this phase's stages; barrier;
// 24 MFMA under setprio; VMW; exit barrier.
#define PH(bf, mh, nh, STAGES, VMW)                                           \
  {                                                                           \
    short8 fah[4], fal[4], fbh[2], fbl[2];                                    \
    _Pragma("unroll")                                                         \
    for (int q = 0; q < 4; ++q) {                                             \
      const int rowA = wm + ((mh)*4 + q)*16 + lrow;                           \
      const int so = rowA*64 + (lq ^ (rowA & 7))*8;                           \
      fah[q] = *(const short8*)&As[bf][so];                                   \
      fal[q] = *(const short8*)&As[bf][so ^ 32];                              \
    }                                                                         \
    _Pragma("unroll")                                                         \
    for (int p = 0; p < 2; ++p) {                                             \
      const int rowB = wn + ((nh)*2 + p)*16 + lrow;                           \
      const int so = rowB*64 + (lq ^ (rowB & 7))*8;                           \
      fbh[p] = *(const short8*)&Bs[bf][so];                                   \
      fbl[p] = *(const short8*)&Bs[bf][so ^ 32];                              \
    }                                                                         \
    STAGES                                                                    \
    __builtin_amdgcn_sched_barrier(0);                                        \
    __builtin_amdgcn_s_barrier();                                             \
    __builtin_amdgcn_sched_barrier(0);                                        \
    __builtin_amdgcn_s_setprio(1);                                            \
    _Pragma("unroll")                                                         \
    for (int q = 0; q < 4; ++q)                                               \
      _Pragma("unroll")                                                       \
      for (int p = 0; p < 2; ++p)                                             \
        acc[(mh)*4+q][(nh)*2+p] = __builtin_amdgcn_mfma_f32_16x16x32_bf16(    \
            fah[q], fbh[p], acc[(mh)*4+q][(nh)*2+p], 0, 0, 0);                \
    _Pragma("unroll")                                                         \
    for (int q = 0; q < 4; ++q)                                               \
      _Pragma("unroll")                                                       \
      for (int p = 0; p < 2; ++p)                                             \
        acc[(mh)*4+q][(nh)*2+p] = __builtin_amdgcn_mfma_f32_16x16x32_bf16(    \
            fah[q], fbl[p], acc[(mh)*4+q][(nh)*2+p], 0, 0, 0);                \
    _Pragma("unroll")                                                         \
    for (int q = 0; q < 4; ++q)                                               \
      _Pragma("unroll")                                                       \
      for (int p = 0; p < 2; ++p)                                             \
        acc[(mh)*4+q][(nh)*2+p] = __builtin_amdgcn_mfma_f32_16x16x32_bf16(    \
            fal[q], fbh[p], acc[(mh)*4+q][(nh)*2+p], 0, 0, 0);                \
    __builtin_amdgcn_s_setprio(0);                                            \
    VMW                                                                       \
    __builtin_amdgcn_sched_barrier(0);                                        \
    __builtin_amdgcn_s_barrier();                                             \
    __builtin_amdgcn_sched_barrier(0);                                        \
  }

    // ---- prologue: tile0 -> buf0 (8 chunk-sets), tile1 -> buf1 alpha+gamma --
    STG_A(0, 0, 0);  STG_A(0, 128, 0);     // A-alpha t0
    STG_A(0, 64, 0); STG_A(0, 192, 0);     // A-beta  t0
    STG_B(0, 0, 0);  STG_B(0, 128, 0);     // B-gamma t0
    STG_B(0, 32, 0); STG_B(0, 160, 0);     // B-delta t0
    STG_A(1, 0, 1);  STG_A(1, 128, 1);     // t1 A-alpha
    STG_B(1, 0, 1);  STG_B(1, 128, 1);     // t1 B-gamma
    asm volatile("s_waitcnt vmcnt(4)" ::: "memory");   // tile0 landed; t1 in flight
    __builtin_amdgcn_sched_barrier(0);
    __builtin_amdgcn_s_barrier();
    __builtin_amdgcn_sched_barrier(0);

    // Stage ledger (steady state, per wave): at p3's VM4 the 8 drained oldest
    // are {prev p6,p7 (buf1 alpha/gamma), this p0,p1 (buf1 beta/delta)} ->
    // phases 4-7's buf1 reads safe; at p7's VM4 drained = {p2..p5: all buf0
    // tE chunks} -> next iter phases 0-3 safe. Write-over-read: each chunk's
    // stage is issued >=1 exit-barrier after its last reader's consuming MFMA.
    #pragma unroll 1
    for (int j = 0; j < 7; ++j) {
        const int tO = 2*j + 1, tE = 2*j + 2, tN = 2*j + 3;
        PH(0, 0, 0, { STG_A(1, 64, tO); STG_A(1, 192, tO); }, VM_NONE)
        PH(0, 0, 1, { STG_B(1, 32, tO); STG_B(1, 160, tO); }, VM_NONE)
        PH(0, 1, 0, { STG_A(0, 0, tE); STG_A(0, 128, tE); }, VM_NONE)
        PH(0, 1, 1, { STG_B(0, 0, tE); STG_B(0, 128, tE); }, VM4)
        PH(1, 0, 0, { STG_A(0, 64, tE); STG_A(0, 192, tE); }, VM_NONE)
        PH(1, 0, 1, { STG_B(0, 32, tE); STG_B(0, 160, tE); }, VM_NONE)
        PH(1, 1, 0, { STG_A(1, 0, tN); STG_A(1, 128, tN); }, VM_NONE)
        PH(1, 1, 1, { STG_B(1, 0, tN); STG_B(1, 128, tN); }, VM4)
    }
    // ---- peeled last iteration (tiles 14=buf0, 15=buf1) ----
    PH(0, 0, 0, { STG_A(1, 64, 15); STG_A(1, 192, 15); }, VM_NONE)
    PH(0, 0, 1, { STG_B(1, 32, 15); STG_B(1, 160, 15); }, VM_NONE)
    PH(0, 1, 0, {}, VM_NONE)
    PH(0, 1, 1, {}, VM0)          // drain everything before buf1 t15 phases
    PH(1, 0, 0, {}, VM_NONE)
    PH(1, 0, 1, {}, VM_NONE)
    PH(1, 1, 0, {}, VM_NONE)
    PH(1, 1, 1, {}, VM_NONE)

#undef PH
#undef VM4
#undef VM0
#undef VM_NONE
#undef STG_A
#undef STG_B

    const float wq = 0.5f / fmaxf(var_q[0], 1e-10f);
    #pragma unroll
    for (int nt = 0; nt < 4; ++nt) {
        const int gcol = n0 + wn + nt * 16 + lrow;
        const float cn = cnorm[gcol];
        #pragma unroll
        for (int mt = 0; mt < 8; ++mt) {
            #pragma unroll
            for (int r = 0; r < 4; ++r) {
                const int grow = m0 + wm + mt * 16 + lq * 4 + r;
                logit[(size_t)grow * KCODES + gcol] = wq * (2.0f * acc[mt][nt][r] - cn);
            }
        }
    }
}

// ---------------- K3: fused stats + colsum + encodings ----------------
// 1024 blocks, 4 blocks/CU. Partials into the dead second halves of each
// block's own lo-row logit slots.
#define PROCESS_ROW(rr, garr)                                               \
  {                                                                         \
    const int rowi = (rr);                                                  \
    const float* lrowp = logit + (size_t)rowi * KCODES;                     \
    float l[32];                                                            \
    _Pragma("unroll")                                                       \
    for (int j = 0; j < 8; ++j) {                                           \
        float4 v = *(const float4*)(lrowp + t * 4 + j * 1024);              \
        l[j*4+0] = v.x; l[j*4+1] = v.y; l[j*4+2] = v.z; l[j*4+3] = v.w;     \
    }                                                                       \
    float m1 = -3.0e38f, m2 = -3.0e38f;                                     \
    _Pragma("unroll")                                                       \
    for (int e = 0; e < 32; ++e) {                                          \
        m1 = fmaxf(m1, l[e]);                                               \
        m2 = fmaxf(m2, (l[e] + garr[e]) * 2.0f);                            \
    }                                                                       \
    red2max(m1, m2, red);                                                   \
    float s1 = 0.f, t1 = 0.f, s2 = 0.f;                                     \
    _Pragma("unroll")                                                       \
    for (int e = 0; e < 32; ++e) {                                          \
        float x  = l[e] - m1;                                               \
        float y  = (l[e] + garr[e]) * 2.0f - m2;                            \
        float e1 = __expf(x);                                               \
        float e2 = __expf(y);                                               \
        s1 += e1; t1 += e1 * x; s2 += e2;                                   \
        l[e] = e1; garr[e] = e2;                                            \
    }                                                                       \
    red3sum(s1, t1, s2, red);                                               \
    const float is1 = 1.0f / s1, is2 = 1.0f / s2;                           \
    unsigned short o16[32];                                                 \
    _Pragma("unroll")                                                       \
    for (int e = 0; e < 32; ++e) {                                          \
        csum[e] += l[e] * is1;                                              \
        o16[e] = f2bf(garr[e] * is2);                                       \
    }                                                                       \
    unsigned short* dstp = (unsigned short*)logit + (size_t)rowi * (2 * KCODES); \
    _Pragma("unroll")                                                       \
    for (int j = 0; j < 8; ++j)                                             \
        *(ushort4*)(dstp + t * 4 + j * 1024) = *(ushort4*)&o16[j * 4];      \
    if (t == 0) kld += t1 * is1 - __logf(s1);                               \
  }

__global__ __launch_bounds__(256) void k_fused(float* __restrict__ logit,
                                               float* __restrict__ acc) {
    __shared__ float red[12];
    __shared__ float ghi[KCODES];   // pending gumbels for row r+2048
    const int b = blockIdx.x;       // 0..1023
    const int t = threadIdx.x;
    float csum[32];
    #pragma unroll
    for (int e = 0; e < 32; ++e) csum[e] = 0.f;
    float kld = 0.f;

    for (int i = 0; i < 2; ++i) {
        const int r_lo = b * 2 + i;       // < 2048
        const int r_hi = r_lo + 2048;

        float g_lo[32];
        #pragma unroll
        for (int j = 0; j < 8; ++j)
            #pragma unroll
            for (int e4 = 0; e4 < 4; ++e4) {
                const uint32_t col = (uint32_t)(t * 4 + j * 1024 + e4);
                const uint32_t jg  = (uint32_t)r_lo * (uint32_t)KCODES + col;
                uint32_t b0, b1;
                threefry2(jg, jg + HALF_NK, b0, b1);
                g_lo[j*4+e4] = gum(b0);
                ghi[col] = gum(b1);
            }

        PROCESS_ROW(r_lo, g_lo)

        float g_hi[32];
        #pragma unroll
        for (int j = 0; j < 8; ++j)
            #pragma unroll
            for (int e4 = 0; e4 < 4; ++e4)
                g_hi[j*4+e4] = ghi[t * 4 + j * 1024 + e4];

        PROCESS_ROW(r_hi, g_hi)
    }

    // partial colsum -> dead second halves of this block's own lo-row slots.
    // cols t*4+j*1024: j<4 -> col<4096 (slot 2b), j>=4 -> col>=4096 (slot 2b+1)
    float* pa = logit + (size_t)(2 * b) * KCODES + (KCODES / 2);
    float* pb = logit + (size_t)(2 * b + 1) * KCODES + (KCODES / 2);
    #pragma unroll
    for (int j = 0; j < 4; ++j)
        *(float4*)&pa[t * 4 + j * 1024] =
            make_float4(csum[j*4], csum[j*4+1], csum[j*4+2], csum[j*4+3]);
    #pragma unroll
    for (int j = 4; j < 8; ++j)
        *(float4*)&pb[t * 4 + (j - 4) * 1024] =
            make_float4(csum[j*4], csum[j*4+1], csum[j*4+2], csum[j*4+3]);
    if (t == 0) atomicAdd(acc + 0, kld);
}

// ---------------- K4: k_mid — gemm2 (pipelined) + colsum stage 1 ------------
// blocks [0,512):  gemm2 z_hat = enc16 @ cbT^T, tile 64x128, BK=64, ksplit 2.
//   Double-buffered LDS, STAGE(next) before compute(cur), one __syncthreads
//   per K-step (drain hidden under 16 MFMA + 12 ds_read).
// blocks [512,1024): colsum stage 1 (1024 in-logit partials -> S[16][8192]).
#define BK2 64
__global__ __launch_bounds__(256) void k_mid(const unsigned short* __restrict__ enc16,
                                             const unsigned short* __restrict__ cbT,
                                             float* __restrict__ outA,
                                             float* __restrict__ out,
                                             float* __restrict__ S) {
    __shared__ __align__(16) unsigned short AS[2][64 * BK2];    // 2 x 8 KB
    __shared__ __align__(16) unsigned short BS[2][128 * BK2];   // 2 x 16 KB
    const int b = blockIdx.x;
    const int t = threadIdx.x;

    if (b >= 512) {
        // ---- tail1 role: sum 64 partials for 256 columns ----
        const int bb2 = b - 512;
        const int g = bb2 >> 5;          // 0..15 partial-group
        const int w = bb2 & 31;          // 0..31 column window
        const int col = w * 256 + t;
        const float* logit = (const float*)enc16;
        const float* base = logit + (size_t)(col >= 4096 ? KCODES : 0)
                          + (KCODES / 2) + (col & 4095);
        float s = 0.f;
        #pragma unroll 8
        for (int bb = g * 64; bb < g * 64 + 64; ++bb)
            s += base[(size_t)bb * (2 * KCODES)];
        S[(size_t)g * KCODES + col] = s;
        return;
    }

    // ---- gemm2 role ----
    const int x   = b & 3;
    const int y   = (b >> 2) & 63;
    const int z   = b >> 8;
    const int n0  = x * 128;
    const int m0  = y * 64;
    const int kz0 = z * (KCODES / 2);
    float* dstC   = z ? out : outA;
    const int w    = t >> 6;
    const int lane = t & 63;
    const int wm   = (w >> 1) * 32;
    const int wn   = (w & 1) * 64;
    const int lrow = lane & 15;
    const int lq   = lane >> 4;
    const int srow = lane >> 3;                    // staging row 0..7 in chunk
    const int ssl  = (lane & 7) ^ (lane >> 3);     // logical slot (XOR swizzle)
    const int scol = ssl * 8;                      // pre-swizzled k-offset

    const unsigned short* Asrc = enc16 + (size_t)(m0 + srow) * (2 * KCODES) + scol;
    const unsigned short* Bsrc = cbT   + (size_t)(n0 + srow) * KCODES + scol;

#define STG2(bf, kt)                                                          \
    {                                                                         \
        _Pragma("unroll")                                                     \
        for (int j = 0; j < 2; ++j) {                                         \
            const int ja = w * 2 + j;                                         \
            cp16(Asrc + (size_t)(ja * 8) * (2 * KCODES) + (kt), &AS[bf][ja * 512]); \
        }                                                                     \
        _Pragma("unroll")                                                     \
        for (int j = 0; j < 4; ++j) {                                         \
            const int jb = w * 4 + j;                                         \
            cp16(Bsrc + (size_t)(jb * 8) * KCODES + (kt), &BS[bf][jb * 512]); \
        }                                                                     \
    }

    f32x4 acc[2][4];
    #pragma unroll
    for (int i = 0; i < 2; ++i)
        #pragma unroll
        for (int j = 0; j < 4; ++j)
            acc[i][j] = (f32x4){0.f, 0.f, 0.f, 0.f};

    // prologue: stage tile 0
    STG2(0, kz0)
    __syncthreads();           // implicit vmcnt(0) drain + barrier

    int buf = 0;
    #pragma unroll 1
    for (int kt = kz0; kt < kz0 + KCODES / 2; kt += BK2) {
        if (kt + BK2 < kz0 + KCODES / 2)
            STG2(buf ^ 1, kt + BK2)          // issue next-tile loads FIRST

        #pragma unroll
        for (int chunk = 0; chunk < 2; ++chunk) {
            short8 af[2];
            #pragma unroll
            for (int mt = 0; mt < 2; ++mt) {
                const int rowA = wm + mt * 16 + lrow;
                af[mt] = *(const short8*)&AS[buf][rowA * BK2 + ((chunk * 4 + lq) ^ (rowA & 7)) * 8];
            }
            #pragma unroll
            for (int nt = 0; nt < 4; ++nt) {
                const int rowB = wn + nt * 16 + lrow;
                const short8 bf = *(const short8*)&BS[buf][rowB * BK2 + ((chunk * 4 + lq) ^ (rowB & 7)) * 8];
                #pragma unroll
                for (int mt = 0; mt < 2; ++mt)
                    acc[mt][nt] = __builtin_amdgcn_mfma_f32_16x16x32_bf16(af[mt], bf, acc[mt][nt], 0, 0, 0);
            }
        }

        __syncthreads();       // drains this iter's stage loads (overlapped above)
        buf ^= 1;
    }
#undef STG2

    #pragma unroll
    for (int mt = 0; mt < 2; ++mt)
        #pragma unroll
        for (int nt = 0; nt < 4; ++nt)
            #pragma unroll
            for (int r = 0; r < 4; ++r) {
                const int grow = m0 + wm + mt * 16 + lq * 4 + r;
                const int gcol = n0 + wn + nt * 16 + lrow;
                dstC[(size_t)grow * DDIM + gcol] = acc[mt][nt][r];
            }
}

// ---------------- K5: tail2 (entropy from S + out-combine + cont. KLD) ------
// blocks [0,32): column entropy from S[16][8192] (16 adds per column)
// blocks [32,544): out = out + outA, accumulate (z - out)^2
__global__ __launch_bounds__(256) void k_tail2(const float* __restrict__ S,
                                               const float* __restrict__ z,
                                               const float* __restrict__ outA,
                                               float* __restrict__ out,
                                               float* __restrict__ acc) {
    __shared__ float red[4];
    const int b = blockIdx.x;
    const int t = threadIdx.x;
    if (b < 32) {
        const int col = b * 256 + t;
        float s = 0.f;
        #pragma unroll
        for (int g = 0; g < 16; ++g)
            s += S[(size_t)g * KCODES + col];
        float a = s * INV_N;
        float ent = a * __logf(a + 1e-7f);
        ent = blockReduce1(ent, red);
        if (t == 0) atomicAdd(acc + 2, ent);
    } else {
        const size_t base = (size_t)(b - 32) * 4096 + t * 4;
        float p = 0.f;
        #pragma unroll
        for (int j = 0; j < 4; ++j) {
            const size_t idx = base + j * 1024;
            float4 o1 = *(const float4*)(out + idx);
            float4 o2 = *(const float4*)(outA + idx);
            float4 zv = *(const float4*)(z + idx);
            float4 s4;
            s4.x = o1.x + o2.x; s4.y = o1.y + o2.y;
            s4.z = o1.z + o2.z; s4.w = o1.w + o2.w;
            *(float4*)(out + idx) = s4;
            float dx = zv.x - s4.x, dy = zv.y - s4.y;
            float dz = zv.z - s4.z, dw = zv.w - s4.w;
            p += dx*dx + dy*dy + dz*dz + dw*dw;
        }
        p = blockReduce1(p, red);
        if (t == 0) atomicAdd(acc + 1, p);
    }
}

// ---------------- K6: finalize ----------------
__global__ __launch_bounds__(64) void k_final(const float* __restrict__ acc,
                                              const float* __restrict__ var_q,
                                              float* __restrict__ out) {
    if (threadIdx.x == 0) {
        float w = 0.5f / fmaxf(var_q[0], 1e-10f);
        float loss = acc[0] / BS_F + acc[1] * w / BS_F;
        out[(size_t)N_ROWS * DDIM]     = loss;
        out[(size_t)N_ROWS * DDIM + 1] = expf(-acc[2]);
    }
}

// ---------------- launch ----------------
extern "C" void kernel_launch(void* const* d_in, const int* in_sizes, int n_in,
                              void* d_out, int out_size, void* d_ws, size_t ws_size,
                              hipStream_t stream) {
    const float* z     = (const float*)d_in[0];
    const float* var_q = (const float*)d_in[1];
    const float* cb    = (const float*)d_in[2];
    float* out = (float*)d_out;
    float* ws  = (float*)d_ws;
    if (ws_size < (size_t)WS_FLOATS * sizeof(float)) return;  // need ~168 MB

    float* logit  = ws + OFF_LOGIT;
    float* cnorm  = ws + OFF_CNORM;
    float* accp   = ws + OFF_ACC;
    unsigned short* zh  = (unsigned short*)(ws + OFF_ZH);
    unsigned short* zl  = (unsigned short*)(ws + OFF_ZL);
    unsigned short* cbh = (unsigned short*)(ws + OFF_CBH);
    unsigned short* cbl = (unsigned short*)(ws + OFF_CBL);
    unsigned short* cbT = (unsigned short*)(ws + OFF_CBT);
    float* outA = ws + OFF_CBL;   // cbl reused after gemm1 (8MB)
    float* S    = ws + OFF_ZH;    // zh reused after gemm1 (512KB of 4MB)

    k_prep  <<<4097, 256, 0, stream>>>(z, cb, zh, zl, cbh, cbl, cbT, cnorm, accp);
    k_gemm1 <<<512, 512, 0, stream>>>(zh, zl, cbh, cbl, cnorm, var_q, logit);
    k_fused <<<1024, 256, 0, stream>>>(logit, accp);
    k_mid   <<<1024, 256, 0, stream>>>((const unsigned short*)logit, cbT, outA, out, S);
    k_tail2 <<<544, 256, 0, stream>>>(S, z, outA, out, accp);
    k_final <<<1, 64, 0, stream>>>(accp, var_q, out);
}

// Round 9
// 358.059 us; speedup vs baseline: 1.0053x; 1.0053x over previous
//
#include <hip/hip_runtime.h>
#include <stdint.h>

// ---------------- problem constants ----------------
#define N_ROWS 4096      // bs*seq = 8*512
#define DDIM   512
#define KCODES 8192
#define NK     (N_ROWS * KCODES)   // 33,554,432
#define HALF_NK 16777216u
#define BS_F   8.0f
#define INV_N  (1.0f / 4096.0f)

// ---------------- ws layout (float offsets) ----------------
// logit region (NK floats): row n's 32KB slot holds (after k_fused)
//   [0,16KB):  bf16 encodings for row n  (read by k_mid gemm2-role)
//   [16KB,32KB): for slots n<2048: colsum partial fragment (read by k_mid tail1-role)
// part[b][c] (b<1024): c<4096 -> slot 2b second half; c>=4096 -> slot 2b+1.
// zh region (dead after gemm1) hosts S[16][8192] second-level colsums (512KB).
// cbl (8MB) reused as outA (gemm2 k-split partial 0) after gemm1.
#define OFF_LOGIT   0
#define OFF_CNORM   (NK)
#define OFF_ACC     (OFF_CNORM + KCODES)   // [0]=sum p*logp, [1]=sum (z-zhat)^2, [2]=entropy
#define OFF_ZH      (OFF_ACC + 4)                    // bf16 z hi  [4096*512]
#define OFF_ZL      (OFF_ZH + (N_ROWS*DDIM/2))       // bf16 z lo
#define OFF_CBH     (OFF_ZL + (N_ROWS*DDIM/2))       // bf16 cb hi [8192*512]
#define OFF_CBL     (OFF_CBH + (KCODES*DDIM/2))      // bf16 cb lo
#define OFF_CBT     (OFF_CBL + (KCODES*DDIM/2))      // bf16 cb^T  [512*8192]
#define WS_FLOATS   (OFF_CBT + (DDIM*KCODES/2))      // ~168MB

typedef __attribute__((ext_vector_type(8))) short short8;
typedef __attribute__((ext_vector_type(4))) float f32x4;

__device__ __forceinline__ unsigned short f2bf(float x) {
    uint32_t u = __float_as_uint(x);
    u += 0x7fffu + ((u >> 16) & 1u);
    return (unsigned short)(u >> 16);
}

// async global->LDS, 16B per lane; lds base must be wave-uniform,
// lane i lands at lds + i*16 (no padding allowed in the chunk).
__device__ __forceinline__ void cp16(const unsigned short* g, unsigned short* l) {
    __builtin_amdgcn_global_load_lds(
        (const __attribute__((address_space(1))) void*)g,
        (__attribute__((address_space(3))) void*)l, 16, 0, 0);
}

// ---------------- JAX threefry2x32-20, key(42) = (0,42) ----------------
__device__ __forceinline__ uint32_t rotl32(uint32_t x, int r) {
    return (x << r) | (x >> (32 - r));
}

__device__ __forceinline__ void threefry2(uint32_t c0, uint32_t c1,
                                          uint32_t& o0, uint32_t& o1) {
    const uint32_t ks0 = 0u, ks1 = 42u, ks2 = 0x1BD11BDAu ^ 0u ^ 42u;
    uint32_t x0 = c0 + ks0;
    uint32_t x1 = c1 + ks1;
#define TF_R(r) { x0 += x1; x1 = rotl32(x1, r); x1 ^= x0; }
    TF_R(13) TF_R(15) TF_R(26) TF_R(6)
    x0 += ks1; x1 += ks2 + 1u;
    TF_R(17) TF_R(29) TF_R(16) TF_R(24)
    x0 += ks2; x1 += ks0 + 2u;
    TF_R(13) TF_R(15) TF_R(26) TF_R(6)
    x0 += ks0; x1 += ks1 + 3u;
    TF_R(17) TF_R(29) TF_R(16) TF_R(24)
    x0 += ks1; x1 += ks2 + 4u;
    TF_R(13) TF_R(15) TF_R(26) TF_R(6)
    x0 += ks2; x1 += ks0 + 5u;
#undef TF_R
    o0 = x0; o1 = x1;
}

__device__ __forceinline__ float u01(uint32_t bits) {
    return __uint_as_float((bits >> 9) | 0x3f800000u) - 1.0f;
}

__device__ __forceinline__ float gum(uint32_t bits) {
    float u = u01(bits);
    return -__logf(-__logf(u + 1e-10f) + 1e-10f);
}

// ---------------- block reduce helpers (256 threads = 4 waves) ----------------
__device__ __forceinline__ float blockReduce1(float v, float* red) {
    #pragma unroll
    for (int o = 32; o > 0; o >>= 1) v += __shfl_down(v, o);
    __syncthreads();
    if ((threadIdx.x & 63) == 0) red[threadIdx.x >> 6] = v;
    __syncthreads();
    return red[0] + red[1] + red[2] + red[3];
}

__device__ __forceinline__ void red2max(float& a, float& b, float* red) {
    #pragma unroll
    for (int o = 32; o > 0; o >>= 1) {
        a = fmaxf(a, __shfl_down(a, o));
        b = fmaxf(b, __shfl_down(b, o));
    }
    __syncthreads();
    if ((threadIdx.x & 63) == 0) {
        red[(threadIdx.x >> 6) * 2 + 0] = a;
        red[(threadIdx.x >> 6) * 2 + 1] = b;
    }
    __syncthreads();
    a = fmaxf(fmaxf(red[0], red[2]), fmaxf(red[4], red[6]));
    b = fmaxf(fmaxf(red[1], red[3]), fmaxf(red[5], red[7]));
}

__device__ __forceinline__ void red3sum(float& a, float& b, float& c, float* red) {
    #pragma unroll
    for (int o = 32; o > 0; o >>= 1) {
        a += __shfl_down(a, o);
        b += __shfl_down(b, o);
        c += __shfl_down(c, o);
    }
    __syncthreads();
    if ((threadIdx.x & 63) == 0) {
        red[(threadIdx.x >> 6) * 3 + 0] = a;
        red[(threadIdx.x >> 6) * 3 + 1] = b;
        red[(threadIdx.x >> 6) * 3 + 2] = c;
    }
    __syncthreads();
    a = red[0] + red[3] + red[6] + red[9];
    b = red[1] + red[4] + red[7] + red[10];
    c = red[2] + red[5] + red[8] + red[11];
}

// ---------------- K1: fused prep ----------------
__global__ __launch_bounds__(256) void k_prep(const float* __restrict__ z,
                                              const float* __restrict__ cb,
                                              unsigned short* __restrict__ zh,
                                              unsigned short* __restrict__ zl,
                                              unsigned short* __restrict__ cbh,
                                              unsigned short* __restrict__ cbl,
                                              unsigned short* __restrict__ cbT,
                                              float* __restrict__ cnorm,
                                              float* __restrict__ accp) {
    __shared__ unsigned short TT[64][65];
    const int b = blockIdx.x;
    const int t = threadIdx.x;
    if (b < 3072) {
        const bool isz = (b < 1024);
        const int bb = isz ? b : b - 1024;
        const float* src = isz ? z : cb;
        unsigned short* hi = isz ? zh : cbh;
        unsigned short* lo = isz ? zl : cbl;
        const size_t idx = ((size_t)bb * 256 + t) * 8;
        float4 a = *(const float4*)(src + idx);
        float4 bv = *(const float4*)(src + idx + 4);
        float f[8] = {a.x, a.y, a.z, a.w, bv.x, bv.y, bv.z, bv.w};
        unsigned short h8[8], l8[8];
        float s = 0.f;
        #pragma unroll
        for (int e = 0; e < 8; ++e) {
            unsigned short h = f2bf(f[e]);
            float hf = __uint_as_float((uint32_t)h << 16);
            h8[e] = h;
            l8[e] = f2bf(f[e] - hf);
            s += f[e] * f[e];
        }
        *(short8*)(hi + idx) = *(short8*)h8;
        *(short8*)(lo + idx) = *(short8*)l8;
        if (!isz) {
            #pragma unroll
            for (int o = 32; o > 0; o >>= 1) s += __shfl_down(s, o);
            if ((t & 63) == 0) cnorm[bb * 4 + (t >> 6)] = s;
        }
    } else if (b < 4096) {
        const int b3 = b - 3072;
        const int k0 = (b3 & 127) * 64;
        const int d0 = (b3 >> 7) * 64;
        #pragma unroll
        for (int j = 0; j < 4; ++j) {
            const int unit = t + j * 256;
            const int r = unit >> 4;
            const int s4 = unit & 15;
            float4 v = *(const float4*)(cb + (size_t)(k0 + r) * DDIM + d0 + s4 * 4);
            TT[r][s4*4+0] = f2bf(v.x); TT[r][s4*4+1] = f2bf(v.y);
            TT[r][s4*4+2] = f2bf(v.z); TT[r][s4*4+3] = f2bf(v.w);
        }
        __syncthreads();
        #pragma unroll
        for (int j = 0; j < 2; ++j) {
            const int unit = t + j * 256;
            const int dr = unit >> 3;
            const int ks = (unit & 7) * 8;
            unsigned short o8[8];
            #pragma unroll
            for (int i = 0; i < 8; ++i) o8[i] = TT[ks + i][dr];
            *(short8*)(cbT + (size_t)(d0 + dr) * KCODES + k0 + ks) = *(short8*)o8;
        }
    } else {
        if (t < 4) accp[t] = 0.f;
    }
}

// ---------------- K2: GEMM1 — 256x256, 8 waves, prefetch-into-MFMA ----------
// Best-measured form (R3/R7: 112.6us, MfmaUtil 38.5, 915 TF = the known
// m97-structure plateau). R8's 8-phase quadrant schedule measured WORSE
// (120us). Parked here permanently; scheduling probes exhausted (R2/R3/R8).
__global__ __launch_bounds__(512, 2)
void k_gemm1(const unsigned short* __restrict__ zh,
             const unsigned short* __restrict__ zl,
             const unsigned short* __restrict__ cbh,
             const unsigned short* __restrict__ cbl,
             const float* __restrict__ cnorm,
             const float* __restrict__ var_q,
             float* __restrict__ logit) {
    __shared__ __align__(1024) unsigned short As[2][256 * 64];   // 2 x 32KB
    __shared__ __align__(1024) unsigned short Bs[2][256 * 64];   // 2 x 32KB

    const int t    = threadIdx.x;           // 0..511
    const int wid  = t >> 6;                // 0..7
    const int lane = t & 63;
    const int lrow = lane & 15;
    const int lq   = lane >> 4;
    const int wm   = (wid >> 2) * 128;      // 2 M-waves
    const int wn   = (wid & 3) * 64;        // 4 N-waves

    // XCD n-slab mapping: x = bid&7 -> n-tiles [4x,4x+4); local covers 16m x 4n
    const int bid   = blockIdx.x;
    const int x     = bid & 7;
    const int local = bid >> 3;
    const int m_t   = (local & 7) | ((local >> 5) << 3);
    const int n_t   = x * 4 + ((local >> 3) & 3);
    const int m0 = m_t * 256;
    const int n0 = n_t * 256;

    // staging source swizzle: lane writes phys slot (lane&7) of row (+lane>>3);
    // logical slot = (lane&7) ^ (lane>>3): <4 -> hi kquad, >=4 -> lo kquad.
    const int sl = (lane & 7) ^ (lane >> 3);
    const unsigned short* asrc = (sl < 4 ? zh : zl) + (sl & 3) * 8;
    const unsigned short* bsrc = (sl < 4 ? cbh : cbl) + (sl & 3) * 8;
    const int rA = (wid << 3) + (lane >> 3);                        // A row offset
    const int rB = ((wid & 3) << 3) + ((wid >> 2) << 6) + (lane >> 3); // B row offset

#define STG_A(bf, ab, kt)                                                     \
    cp16(asrc + (size_t)(m0 + (ab) + rA) * 512 + (kt) * 32,                   \
         &As[bf][((ab) + (wid << 3)) * 64])
#define STG_B(bf, bb_, kt)                                                    \
    cp16(bsrc + (size_t)(n0 + (bb_) + rB) * 512 + (kt) * 32,                  \
         &Bs[bf][((bb_) + ((wid & 3) << 3) + ((wid >> 2) << 6)) * 64])

    f32x4 acc[8][4];
    #pragma unroll
    for (int i = 0; i < 8; ++i)
        #pragma unroll
        for (int jj = 0; jj < 4; ++jj)
            acc[i][jj] = (f32x4){0.f, 0.f, 0.f, 0.f};

    short8 a0h[4], a0l[4];   // A frag set 0 (ping)
    short8 a1h[4], a1l[4];   // A frag set 1 (pong)
    short8 fb[4];            // B frag (single buffer, hi/lo time-shared)

#define RD_A(DH, DL, bf, mh)                                                  \
    _Pragma("unroll")                                                         \
    for (int q = 0; q < 4; ++q) {                                             \
      const int rowA = wm + (mh)*64 + q*16 + lrow;                            \
      const int so = rowA*64 + (lq ^ (rowA & 7))*8;                           \
      DH[q] = *(const short8*)&As[bf][so];                                    \
      DL[q] = *(const short8*)&As[bf][so ^ 32];                               \
    }
#define RD_BH(bf)                                                             \
    _Pragma("unroll")                                                         \
    for (int p = 0; p < 4; ++p) {                                             \
      const int rowB = wn + p*16 + lrow;                                      \
      const int so = rowB*64 + (lq ^ (rowB & 7))*8;                           \
      fb[p] = *(const short8*)&Bs[bf][so];                                    \
    }
#define RD_BL(bf)                                                             \
    _Pragma("unroll")                                                         \
    for (int p = 0; p < 4; ++p) {                                             \
      const int rowB = wn + p*16 + lrow;                                      \
      const int so = (rowB*64 + (lq ^ (rowB & 7))*8) ^ 32;                    \
      fb[p] = *(const short8*)&Bs[bf][so];                                    \
    }
#define MFMA16(AR, mh)                                                        \
    _Pragma("unroll")                                                         \
    for (int q = 0; q < 4; ++q)                                               \
      _Pragma("unroll")                                                       \
      for (int p = 0; p < 4; ++p)                                             \
        acc[(mh)*4+q][p] = __builtin_amdgcn_mfma_f32_16x16x32_bf16(           \
            AR[q], fb[p], acc[(mh)*4+q][p], 0, 0, 0);

#define VM2 asm volatile("s_waitcnt vmcnt(2)" ::: "memory");
#define VM0 asm volatile("s_waitcnt vmcnt(0)" ::: "memory");

// EVEN phase (mh0): fb enters holding Bh(cur). Order: t1(Ah*Bh), prefetch
// next-A, t3(Al*Bh), fb<-Bl, t2(Ah*Bl). Leaves fb = Bl(cur).
#define PH_EVEN(VMW, STAGES, CH, CL, NH, NL, nbf, bbf)                        \
  {                                                                           \
    VMW                                                                       \
    __builtin_amdgcn_s_barrier();                                             \
    __builtin_amdgcn_sched_barrier(0);                                        \
    STAGES                                                                    \
    __builtin_amdgcn_s_setprio(1);                                            \
    MFMA16(CH, 0)                                                             \
    RD_A(NH, NL, nbf, 1)                                                      \
    MFMA16(CL, 0)                                                             \
    RD_BL(bbf)                                                                \
    MFMA16(CH, 0)                                                             \
    __builtin_amdgcn_s_setprio(0);                                            \
  }
// ODD phase (mh1): fb enters holding Bl(cur). Order: t2(Ah*Bl), prefetch
// next-A, fb<-Bh, t1(Ah*Bh), t3(Al*Bh), TAIL (fb<-Bh of next tile).
#define PH_ODD(VMW, STAGES, CH, CL, NH, NL, nbf, bbf, TAIL)                   \
  {                                                                           \
    VMW                                                                       \
    __builtin_amdgcn_s_barrier();                                             \
    __builtin_amdgcn_sched_barrier(0);                                        \
    STAGES                                                                    \
    __builtin_amdgcn_s_setprio(1);                                            \
    MFMA16(CH, 1)                                                             \
    RD_A(NH, NL, nbf, 0)                                                      \
    RD_BH(bbf)                                                                \
    MFMA16(CH, 1)                                                             \
    MFMA16(CL, 1)                                                             \
    TAIL                                                                      \
    __builtin_amdgcn_s_setprio(0);                                            \
  }

    // ---- prologue ----
    STG_A(0, 0, 0);  STG_A(0, 128, 0);
    STG_B(0, 0, 0);  STG_B(0, 128, 0); STG_B(0, 32, 0); STG_B(0, 160, 0);
    STG_A(0, 64, 0); STG_A(0, 192, 0);
    STG_A(1, 0, 1);  STG_A(1, 128, 1);
    asm volatile("s_waitcnt vmcnt(4)" ::: "memory");  // Aalpha+B landed
    __builtin_amdgcn_s_barrier();
    __builtin_amdgcn_sched_barrier(0);
    RD_A(a0h, a0l, 0, 0);
    RD_BH(0);

    #pragma unroll 1
    for (int j = 0; j < 7; ++j) {
        const int tO = 2*j + 1, tE = 2*j + 2, tN = 2*j + 3;
        PH_EVEN(VM2, { STG_B(1,0,tO); STG_B(1,128,tO); STG_B(1,32,tO); STG_B(1,160,tO);
                       STG_A(1,64,tO); STG_A(1,192,tO); },
                a0h, a0l, a1h, a1l, 0, 0)
        PH_ODD (VM2, { STG_A(0,0,tE); STG_A(0,128,tE); },
                a1h, a1l, a0h, a0l, 1, 0, RD_BH(1))
        PH_EVEN(VM2, { STG_B(0,0,tE); STG_B(0,128,tE); STG_B(0,32,tE); STG_B(0,160,tE);
                       STG_A(0,64,tE); STG_A(0,192,tE); },
                a0h, a0l, a1h, a1l, 1, 1)
        PH_ODD (VM2, { STG_A(1,0,tN); STG_A(1,128,tN); },
                a1h, a1l, a0h, a0l, 0, 1, RD_BH(0))
    }
    // ---- peeled last iteration (tiles 14=buf0, 15=buf1) ----
    PH_EVEN(VM2, { STG_B(1,0,15); STG_B(1,128,15); STG_B(1,32,15); STG_B(1,160,15);
                   STG_A(1,64,15); STG_A(1,192,15); },
            a0h, a0l, a1h, a1l, 0, 0)
    PH_ODD (VM2, {}, a1h, a1l, a0h, a0l, 1, 0, RD_BH(1))
    PH_EVEN(VM0, {}, a0h, a0l, a1h, a1l, 1, 1)
    {   // final ODD (buf1 mh1): no stages, no prefetch, no tail
        __builtin_amdgcn_s_barrier();
        __builtin_amdgcn_sched_barrier(0);
        __builtin_amdgcn_s_setprio(1);
        MFMA16(a1h, 1)
        RD_BH(1)
        MFMA16(a1h, 1)
        MFMA16(a1l, 1)
        __builtin_amdgcn_s_setprio(0);
    }

#undef PH_EVEN
#undef PH_ODD
#undef VM2
#undef VM0
#undef MFMA16
#undef RD_A
#undef RD_BH
#undef RD_BL
#undef STG_A
#undef STG_B

    const float wq = 0.5f / fmaxf(var_q[0], 1e-10f);
    #pragma unroll
    for (int nt = 0; nt < 4; ++nt) {
        const int gcol = n0 + wn + nt * 16 + lrow;
        const float cn = cnorm[gcol];
        #pragma unroll
        for (int mt = 0; mt < 8; ++mt) {
            #pragma unroll
            for (int r = 0; r < 4; ++r) {
                const int grow = m0 + wm + mt * 16 + lq * 4 + r;
                logit[(size_t)grow * KCODES + gcol] = wq * (2.0f * acc[mt][nt][r] - cn);
            }
        }
    }
}

// ---------------- K3: fused stats + colsum + encodings ----------------
// 1024 blocks, 4 blocks/CU. R9: T14 issue-early — the 32KB row load is hoisted
// ABOVE the ~560-op threefry section (r_lo) / above the ghi gather (r_hi), so
// HBM latency hides under independent VALU instead of stalling the max pass.
// VGPR-neutral: peak pressure is in the exp/store phase, unchanged.
#define PR_LOAD(rr, larr)                                                   \
  {                                                                         \
    const float* lrowp = logit + (size_t)(rr) * KCODES;                     \
    _Pragma("unroll")                                                       \
    for (int j = 0; j < 8; ++j) {                                           \
        float4 v = *(const float4*)(lrowp + t * 4 + j * 1024);              \
        larr[j*4+0] = v.x; larr[j*4+1] = v.y;                               \
        larr[j*4+2] = v.z; larr[j*4+3] = v.w;                               \
    }                                                                       \
  }

#define PR_BODY(rr, larr, garr)                                             \
  {                                                                         \
    float m1 = -3.0e38f, m2 = -3.0e38f;                                     \
    _Pragma("unroll")                                                       \
    for (int e = 0; e < 32; ++e) {                                          \
        m1 = fmaxf(m1, larr[e]);                                            \
        m2 = fmaxf(m2, (larr[e] + garr[e]) * 2.0f);                         \
    }                                                                       \
    red2max(m1, m2, red);                                                   \
    float s1 = 0.f, t1 = 0.f, s2 = 0.f;                                     \
    _Pragma("unroll")                                                       \
    for (int e = 0; e < 32; ++e) {                                          \
        float x  = larr[e] - m1;                                            \
        float y  = (larr[e] + garr[e]) * 2.0f - m2;                         \
        float e1 = __expf(x);                                               \
        float e2 = __expf(y);                                               \
        s1 += e1; t1 += e1 * x; s2 += e2;                                   \
        larr[e] = e1; garr[e] = e2;                                         \
    }                                                                       \
    red3sum(s1, t1, s2, red);                                               \
    const float is1 = 1.0f / s1, is2 = 1.0f / s2;                           \
    unsigned short o16[32];                                                 \
    _Pragma("unroll")                                                       \
    for (int e = 0; e < 32; ++e) {                                          \
        csum[e] += larr[e] * is1;                                           \
        o16[e] = f2bf(garr[e] * is2);                                       \
    }                                                                       \
    unsigned short* dstp = (unsigned short*)logit + (size_t)(rr) * (2 * KCODES); \
    _Pragma("unroll")                                                       \
    for (int j = 0; j < 8; ++j)                                             \
        *(ushort4*)(dstp + t * 4 + j * 1024) = *(ushort4*)&o16[j * 4];      \
    if (t == 0) kld += t1 * is1 - __logf(s1);                               \
  }

__global__ __launch_bounds__(256) void k_fused(float* __restrict__ logit,
                                               float* __restrict__ acc) {
    __shared__ float red[12];
    __shared__ float ghi[KCODES];   // pending gumbels for row r+2048
    const int b = blockIdx.x;       // 0..1023
    const int t = threadIdx.x;
    float csum[32];
    #pragma unroll
    for (int e = 0; e < 32; ++e) csum[e] = 0.f;
    float kld = 0.f;

    for (int i = 0; i < 2; ++i) {
        const int r_lo = b * 2 + i;       // < 2048
        const int r_hi = r_lo + 2048;

        float l[32];
        PR_LOAD(r_lo, l)                  // issue loads; latency hides under threefry

        float g_lo[32];
        #pragma unroll
        for (int j = 0; j < 8; ++j)
            #pragma unroll
            for (int e4 = 0; e4 < 4; ++e4) {
                const uint32_t col = (uint32_t)(t * 4 + j * 1024 + e4);
                const uint32_t jg  = (uint32_t)r_lo * (uint32_t)KCODES + col;
                uint32_t b0, b1;
                threefry2(jg, jg + HALF_NK, b0, b1);
                g_lo[j*4+e4] = gum(b0);
                ghi[col] = gum(b1);       // same-thread write; no sync needed
            }

        PR_BODY(r_lo, l, g_lo)

        PR_LOAD(r_hi, l)                  // issue early; hides under gather+max

        float g_hi[32];
        #pragma unroll
        for (int j = 0; j < 8; ++j)
            #pragma unroll
            for (int e4 = 0; e4 < 4; ++e4)
                g_hi[j*4+e4] = ghi[t * 4 + j * 1024 + e4];

        PR_BODY(r_hi, l, g_hi)
    }

    // partial colsum -> dead second halves of this block's own lo-row slots.
    // cols t*4+j*1024: j<4 -> col<4096 (slot 2b), j>=4 -> col>=4096 (slot 2b+1)
    float* pa = logit + (size_t)(2 * b) * KCODES + (KCODES / 2);
    float* pb = logit + (size_t)(2 * b + 1) * KCODES + (KCODES / 2);
    #pragma unroll
    for (int j = 0; j < 4; ++j)
        *(float4*)&pa[t * 4 + j * 1024] =
            make_float4(csum[j*4], csum[j*4+1], csum[j*4+2], csum[j*4+3]);
    #pragma unroll
    for (int j = 4; j < 8; ++j)
        *(float4*)&pb[t * 4 + (j - 4) * 1024] =
            make_float4(csum[j*4], csum[j*4+1], csum[j*4+2], csum[j*4+3]);
    if (t == 0) atomicAdd(acc + 0, kld);
}

// ---------------- K4: k_mid — gemm2 (pipelined) + colsum stage 1 ------------
// blocks [0,512):  gemm2 z_hat = enc16 @ cbT^T, tile 64x128, BK=64, ksplit 2.
//   Double-buffered LDS, STAGE(next) before compute(cur), one __syncthreads
//   per K-step (drain hidden under 16 MFMA + 12 ds_read).
// blocks [512,1024): colsum stage 1 (1024 in-logit partials -> S[16][8192]).
#define BK2 64
__global__ __launch_bounds__(256) void k_mid(const unsigned short* __restrict__ enc16,
                                             const unsigned short* __restrict__ cbT,
                                             float* __restrict__ outA,
                                             float* __restrict__ out,
                                             float* __restrict__ S) {
    __shared__ __align__(16) unsigned short AS[2][64 * BK2];    // 2 x 8 KB
    __shared__ __align__(16) unsigned short BS[2][128 * BK2];   // 2 x 16 KB
    const int b = blockIdx.x;
    const int t = threadIdx.x;

    if (b >= 512) {
        // ---- tail1 role: sum 64 partials for 256 columns ----
        const int bb2 = b - 512;
        const int g = bb2 >> 5;          // 0..15 partial-group
        const int w = bb2 & 31;          // 0..31 column window
        const int col = w * 256 + t;
        const float* logit = (const float*)enc16;
        const float* base = logit + (size_t)(col >= 4096 ? KCODES : 0)
                          + (KCODES / 2) + (col & 4095);
        float s = 0.f;
        #pragma unroll 8
        for (int bb = g * 64; bb < g * 64 + 64; ++bb)
            s += base[(size_t)bb * (2 * KCODES)];
        S[(size_t)g * KCODES + col] = s;
        return;
    }

    // ---- gemm2 role ----
    const int x   = b & 3;
    const int y   = (b >> 2) & 63;
    const int z   = b >> 8;
    const int n0  = x * 128;
    const int m0  = y * 64;
    const int kz0 = z * (KCODES / 2);
    float* dstC   = z ? out : outA;
    const int w    = t >> 6;
    const int lane = t & 63;
    const int wm   = (w >> 1) * 32;
    const int wn   = (w & 1) * 64;
    const int lrow = lane & 15;
    const int lq   = lane >> 4;
    const int srow = lane >> 3;                    // staging row 0..7 in chunk
    const int ssl  = (lane & 7) ^ (lane >> 3);     // logical slot (XOR swizzle)
    const int scol = ssl * 8;                      // pre-swizzled k-offset

    const unsigned short* Asrc = enc16 + (size_t)(m0 + srow) * (2 * KCODES) + scol;
    const unsigned short* Bsrc = cbT   + (size_t)(n0 + srow) * KCODES + scol;

#define STG2(bf, kt)                                                          \
    {                                                                         \
        _Pragma("unroll")                                                     \
        for (int j = 0; j < 2; ++j) {                                         \
            const int ja = w * 2 + j;                                         \
            cp16(Asrc + (size_t)(ja * 8) * (2 * KCODES) + (kt), &AS[bf][ja * 512]); \
        }                                                                     \
        _Pragma("unroll")                                                     \
        for (int j = 0; j < 4; ++j) {                                         \
            const int jb = w * 4 + j;                                         \
            cp16(Bsrc + (size_t)(jb * 8) * KCODES + (kt), &BS[bf][jb * 512]); \
        }                                                                     \
    }

    f32x4 acc[2][4];
    #pragma unroll
    for (int i = 0; i < 2; ++i)
        #pragma unroll
        for (int j = 0; j < 4; ++j)
            acc[i][j] = (f32x4){0.f, 0.f, 0.f, 0.f};

    // prologue: stage tile 0
    STG2(0, kz0)
    __syncthreads();           // implicit vmcnt(0) drain + barrier

    int buf = 0;
    #pragma unroll 1
    for (int kt = kz0; kt < kz0 + KCODES / 2; kt += BK2) {
        if (kt + BK2 < kz0 + KCODES / 2)
            STG2(buf ^ 1, kt + BK2)          // issue next-tile loads FIRST

        #pragma unroll
        for (int chunk = 0; chunk < 2; ++chunk) {
            short8 af[2];
            #pragma unroll
            for (int mt = 0; mt < 2; ++mt) {
                const int rowA = wm + mt * 16 + lrow;
                af[mt] = *(const short8*)&AS[buf][rowA * BK2 + ((chunk * 4 + lq) ^ (rowA & 7)) * 8];
            }
            #pragma unroll
            for (int nt = 0; nt < 4; ++nt) {
                const int rowB = wn + nt * 16 + lrow;
                const short8 bf = *(const short8*)&BS[buf][rowB * BK2 + ((chunk * 4 + lq) ^ (rowB & 7)) * 8];
                #pragma unroll
                for (int mt = 0; mt < 2; ++mt)
                    acc[mt][nt] = __builtin_amdgcn_mfma_f32_16x16x32_bf16(af[mt], bf, acc[mt][nt], 0, 0, 0);
            }
        }

        __syncthreads();       // drains this iter's stage loads (overlapped above)
        buf ^= 1;
    }
#undef STG2

    #pragma unroll
    for (int mt = 0; mt < 2; ++mt)
        #pragma unroll
        for (int nt = 0; nt < 4; ++nt)
            #pragma unroll
            for (int r = 0; r < 4; ++r) {
                const int grow = m0 + wm + mt * 16 + lq * 4 + r;
                const int gcol = n0 + wn + nt * 16 + lrow;
                dstC[(size_t)grow * DDIM + gcol] = acc[mt][nt][r];
            }
}

// ---------------- K5: tail2 (entropy from S + out-combine + cont. KLD) ------
// blocks [0,32): column entropy from S[16][8192] (16 adds per column)
// blocks [32,544): out = out + outA, accumulate (z - out)^2
__global__ __launch_bounds__(256) void k_tail2(const float* __restrict__ S,
                                               const float* __restrict__ z,
                                               const float* __restrict__ outA,
                                               float* __restrict__ out,
                                               float* __restrict__ acc) {
    __shared__ float red[4];
    const int b = blockIdx.x;
    const int t = threadIdx.x;
    if (b < 32) {
        const int col = b * 256 + t;
        float s = 0.f;
        #pragma unroll
        for (int g = 0; g < 16; ++g)
            s += S[(size_t)g * KCODES + col];
        float a = s * INV_N;
        float ent = a * __logf(a + 1e-7f);
        ent = blockReduce1(ent, red);
        if (t == 0) atomicAdd(acc + 2, ent);
    } else {
        const size_t base = (size_t)(b - 32) * 4096 + t * 4;
        float p = 0.f;
        #pragma unroll
        for (int j = 0; j < 4; ++j) {
            const size_t idx = base + j * 1024;
            float4 o1 = *(const float4*)(out + idx);
            float4 o2 = *(const float4*)(outA + idx);
            float4 zv = *(const float4*)(z + idx);
            float4 s4;
            s4.x = o1.x + o2.x; s4.y = o1.y + o2.y;
            s4.z = o1.z + o2.z; s4.w = o1.w + o2.w;
            *(float4*)(out + idx) = s4;
            float dx = zv.x - s4.x, dy = zv.y - s4.y;
            float dz = zv.z - s4.z, dw = zv.w - s4.w;
            p += dx*dx + dy*dy + dz*dz + dw*dw;
        }
        p = blockReduce1(p, red);
        if (t == 0) atomicAdd(acc + 1, p);
    }
}

// ---------------- K6: finalize ----------------
__global__ __launch_bounds__(64) void k_final(const float* __restrict__ acc,
                                              const float* __restrict__ var_q,
                                              float* __restrict__ out) {
    if (threadIdx.x == 0) {
        float w = 0.5f / fmaxf(var_q[0], 1e-10f);
        float loss = acc[0] / BS_F + acc[1] * w / BS_F;
        out[(size_t)N_ROWS * DDIM]     = loss;
        out[(size_t)N_ROWS * DDIM + 1] = expf(-acc[2]);
    }
}

// ---------------- launch ----------------
extern "C" void kernel_launch(void* const* d_in, const int* in_sizes, int n_in,
                              void* d_out, int out_size, void* d_ws, size_t ws_size,
                              hipStream_t stream) {
    const float* z     = (const float*)d_in[0];
    const float* var_q = (const float*)d_in[1];
    const float* cb    = (const float*)d_in[2];
    float* out = (float*)d_out;
    float* ws  = (float*)d_ws;
    if (ws_size < (size_t)WS_FLOATS * sizeof(float)) return;  // need ~168 MB

    float* logit  = ws + OFF_LOGIT;
    float* cnorm  = ws + OFF_CNORM;
    float* accp   = ws + OFF_ACC;
    unsigned short* zh  = (unsigned short*)(ws + OFF_ZH);
    unsigned short* zl  = (unsigned short*)(ws + OFF_ZL);
    unsigned short* cbh = (unsigned short*)(ws + OFF_CBH);
    unsigned short* cbl = (unsigned short*)(ws + OFF_CBL);
    unsigned short* cbT = (unsigned short*)(ws + OFF_CBT);
    float* outA = ws + OFF_CBL;   // cbl reused after gemm1 (8MB)
    float* S    = ws + OFF_ZH;    // zh reused after gemm1 (512KB of 4MB)

    k_prep  <<<4097, 256, 0, stream>>>(z, cb, zh, zl, cbh, cbl, cbT, cnorm, accp);
    k_gemm1 <<<512, 512, 0, stream>>>(zh, zl, cbh, cbl, cnorm, var_q, logit);
    k_fused <<<1024, 256, 0, stream>>>(logit, accp);
    k_mid   <<<1024, 256, 0, stream>>>((const unsigned short*)logit, cbT, outA, out, S);
    k_tail2 <<<544, 256, 0, stream>>>(S, z, outA, out, accp);
    k_final <<<1, 64, 0, stream>>>(accp, var_q, out);
}

// Round 11
// 353.896 us; speedup vs baseline: 1.0172x; 1.0118x over previous
//
#include <hip/hip_runtime.h>
#include <stdint.h>

// ---------------- problem constants ----------------
#define N_ROWS 4096      // bs*seq = 8*512
#define DDIM   512
#define KCODES 8192
#define NK     (N_ROWS * KCODES)   // 33,554,432
#define HALF_NK 16777216u
#define BS_F   8.0f
#define INV_N  (1.0f / 4096.0f)

// ---------------- ws layout (float offsets) ----------------
// logit region (NK floats): row n's 32KB slot holds (after k_fused)
//   [0,16KB):  bf16 encodings for row n  (read by k_mid gemm2-role)
//   [16KB,32KB): for slots n<2048: colsum partial fragment (read by k_mid tail1-role)
// part[b][c] (b<1024): c<4096 -> slot 2b second half; c>=4096 -> slot 2b+1.
// zh region (dead after gemm1) hosts S[16][8192] second-level colsums (512KB).
// cbl (8MB) reused as outA (gemm2 k-split partial 0) after gemm1.
#define OFF_LOGIT   0
#define OFF_CNORM   (NK)
#define OFF_ACC     (OFF_CNORM + KCODES)   // [0]=sum p*logp, [1]=sum (z-zhat)^2, [2]=entropy
#define OFF_ZH      (OFF_ACC + 4)                    // bf16 z hi  [4096*512]
#define OFF_ZL      (OFF_ZH + (N_ROWS*DDIM/2))       // bf16 z lo
#define OFF_CBH     (OFF_ZL + (N_ROWS*DDIM/2))       // bf16 cb hi [8192*512]
#define OFF_CBL     (OFF_CBH + (KCODES*DDIM/2))      // bf16 cb lo
#define OFF_CBT     (OFF_CBL + (KCODES*DDIM/2))      // bf16 cb^T  [512*8192]
#define WS_FLOATS   (OFF_CBT + (DDIM*KCODES/2))      // ~168MB

typedef __attribute__((ext_vector_type(8))) short short8;
typedef __attribute__((ext_vector_type(4))) float f32x4;

__device__ __forceinline__ unsigned short f2bf(float x) {
    uint32_t u = __float_as_uint(x);
    u += 0x7fffu + ((u >> 16) & 1u);
    return (unsigned short)(u >> 16);
}

// async global->LDS, 16B per lane; lds base must be wave-uniform,
// lane i lands at lds + i*16 (no padding allowed in the chunk).
__device__ __forceinline__ void cp16(const unsigned short* g, unsigned short* l) {
    __builtin_amdgcn_global_load_lds(
        (const __attribute__((address_space(1))) void*)g,
        (__attribute__((address_space(3))) void*)l, 16, 0, 0);
}

// ---------------- JAX threefry2x32-20, key(42) = (0,42) ----------------
__device__ __forceinline__ uint32_t rotl32(uint32_t x, int r) {
    return (x << r) | (x >> (32 - r));
}

__device__ __forceinline__ void threefry2(uint32_t c0, uint32_t c1,
                                          uint32_t& o0, uint32_t& o1) {
    const uint32_t ks0 = 0u, ks1 = 42u, ks2 = 0x1BD11BDAu ^ 0u ^ 42u;
    uint32_t x0 = c0 + ks0;
    uint32_t x1 = c1 + ks1;
#define TF_R(r) { x0 += x1; x1 = rotl32(x1, r); x1 ^= x0; }
    TF_R(13) TF_R(15) TF_R(26) TF_R(6)
    x0 += ks1; x1 += ks2 + 1u;
    TF_R(17) TF_R(29) TF_R(16) TF_R(24)
    x0 += ks2; x1 += ks0 + 2u;
    TF_R(13) TF_R(15) TF_R(26) TF_R(6)
    x0 += ks0; x1 += ks1 + 3u;
    TF_R(17) TF_R(29) TF_R(16) TF_R(24)
    x0 += ks1; x1 += ks2 + 4u;
    TF_R(13) TF_R(15) TF_R(26) TF_R(6)
    x0 += ks2; x1 += ks0 + 5u;
#undef TF_R
    o0 = x0; o1 = x1;
}

__device__ __forceinline__ float u01(uint32_t bits) {
    return __uint_as_float((bits >> 9) | 0x3f800000u) - 1.0f;
}

__device__ __forceinline__ float gum(uint32_t bits) {
    float u = u01(bits);
    return -__logf(-__logf(u + 1e-10f) + 1e-10f);
}

// ---------------- block reduce helpers (256 threads = 4 waves) ----------------
__device__ __forceinline__ float blockReduce1(float v, float* red) {
    #pragma unroll
    for (int o = 32; o > 0; o >>= 1) v += __shfl_down(v, o);
    __syncthreads();
    if ((threadIdx.x & 63) == 0) red[threadIdx.x >> 6] = v;
    __syncthreads();
    return red[0] + red[1] + red[2] + red[3];
}

// ---------------- block reduce helpers (512 threads = 8 waves) ----------------
__device__ __forceinline__ void red2max8(float& a, float& b, float* red) {
    #pragma unroll
    for (int o = 32; o > 0; o >>= 1) {
        a = fmaxf(a, __shfl_down(a, o));
        b = fmaxf(b, __shfl_down(b, o));
    }
    __syncthreads();
    if ((threadIdx.x & 63) == 0) {
        red[(threadIdx.x >> 6) * 2 + 0] = a;
        red[(threadIdx.x >> 6) * 2 + 1] = b;
    }
    __syncthreads();
    float a0 = fmaxf(fmaxf(red[0], red[2]), fmaxf(red[4], red[6]));
    float a1 = fmaxf(fmaxf(red[8], red[10]), fmaxf(red[12], red[14]));
    a = fmaxf(a0, a1);
    float b0 = fmaxf(fmaxf(red[1], red[3]), fmaxf(red[5], red[7]));
    float b1 = fmaxf(fmaxf(red[9], red[11]), fmaxf(red[13], red[15]));
    b = fmaxf(b0, b1);
}

__device__ __forceinline__ void red3sum8(float& a, float& b, float& c, float* red) {
    #pragma unroll
    for (int o = 32; o > 0; o >>= 1) {
        a += __shfl_down(a, o);
        b += __shfl_down(b, o);
        c += __shfl_down(c, o);
    }
    __syncthreads();
    if ((threadIdx.x & 63) == 0) {
        red[(threadIdx.x >> 6) * 3 + 0] = a;
        red[(threadIdx.x >> 6) * 3 + 1] = b;
        red[(threadIdx.x >> 6) * 3 + 2] = c;
    }
    __syncthreads();
    a = ((red[0] + red[3]) + (red[6] + red[9]))
      + ((red[12] + red[15]) + (red[18] + red[21]));
    b = ((red[1] + red[4]) + (red[7] + red[10]))
      + ((red[13] + red[16]) + (red[19] + red[22]));
    c = ((red[2] + red[5]) + (red[8] + red[11]))
      + ((red[14] + red[17]) + (red[20] + red[23]));
}

// ---------------- K1: fused prep ----------------
__global__ __launch_bounds__(256) void k_prep(const float* __restrict__ z,
                                              const float* __restrict__ cb,
                                              unsigned short* __restrict__ zh,
                                              unsigned short* __restrict__ zl,
                                              unsigned short* __restrict__ cbh,
                                              unsigned short* __restrict__ cbl,
                                              unsigned short* __restrict__ cbT,
                                              float* __restrict__ cnorm,
                                              float* __restrict__ accp) {
    __shared__ unsigned short TT[64][65];
    const int b = blockIdx.x;
    const int t = threadIdx.x;
    if (b < 3072) {
        const bool isz = (b < 1024);
        const int bb = isz ? b : b - 1024;
        const float* src = isz ? z : cb;
        unsigned short* hi = isz ? zh : cbh;
        unsigned short* lo = isz ? zl : cbl;
        const size_t idx = ((size_t)bb * 256 + t) * 8;
        float4 a = *(const float4*)(src + idx);
        float4 bv = *(const float4*)(src + idx + 4);
        float f[8] = {a.x, a.y, a.z, a.w, bv.x, bv.y, bv.z, bv.w};
        unsigned short h8[8], l8[8];
        float s = 0.f;
        #pragma unroll
        for (int e = 0; e < 8; ++e) {
            unsigned short h = f2bf(f[e]);
            float hf = __uint_as_float((uint32_t)h << 16);
            h8[e] = h;
            l8[e] = f2bf(f[e] - hf);
            s += f[e] * f[e];
        }
        *(short8*)(hi + idx) = *(short8*)h8;
        *(short8*)(lo + idx) = *(short8*)l8;
        if (!isz) {
            #pragma unroll
            for (int o = 32; o > 0; o >>= 1) s += __shfl_down(s, o);
            if ((t & 63) == 0) cnorm[bb * 4 + (t >> 6)] = s;
        }
    } else if (b < 4096) {
        const int b3 = b - 3072;
        const int k0 = (b3 & 127) * 64;
        const int d0 = (b3 >> 7) * 64;
        #pragma unroll
        for (int j = 0; j < 4; ++j) {
            const int unit = t + j * 256;
            const int r = unit >> 4;
            const int s4 = unit & 15;
            float4 v = *(const float4*)(cb + (size_t)(k0 + r) * DDIM + d0 + s4 * 4);
            TT[r][s4*4+0] = f2bf(v.x); TT[r][s4*4+1] = f2bf(v.y);
            TT[r][s4*4+2] = f2bf(v.z); TT[r][s4*4+3] = f2bf(v.w);
        }
        __syncthreads();
        #pragma unroll
        for (int j = 0; j < 2; ++j) {
            const int unit = t + j * 256;
            const int dr = unit >> 3;
            const int ks = (unit & 7) * 8;
            unsigned short o8[8];
            #pragma unroll
            for (int i = 0; i < 8; ++i) o8[i] = TT[ks + i][dr];
            *(short8*)(cbT + (size_t)(d0 + dr) * KCODES + k0 + ks) = *(short8*)o8;
        }
    } else {
        if (t < 4) accp[t] = 0.f;
    }
}

// ---------------- K2: GEMM1 — 256x256, 8 waves, prefetch-into-MFMA ----------
// Best-measured form (R3/R7: 112.6us, MfmaUtil 38.5, 915 TF = the known
// m97-structure plateau). R8's 8-phase quadrant schedule measured WORSE
// (120us). Parked permanently; scheduling probes exhausted (R2/R3/R8).
__global__ __launch_bounds__(512, 2)
void k_gemm1(const unsigned short* __restrict__ zh,
             const unsigned short* __restrict__ zl,
             const unsigned short* __restrict__ cbh,
             const unsigned short* __restrict__ cbl,
             const float* __restrict__ cnorm,
             const float* __restrict__ var_q,
             float* __restrict__ logit) {
    __shared__ __align__(1024) unsigned short As[2][256 * 64];   // 2 x 32KB
    __shared__ __align__(1024) unsigned short Bs[2][256 * 64];   // 2 x 32KB

    const int t    = threadIdx.x;           // 0..511
    const int wid  = t >> 6;                // 0..7
    const int lane = t & 63;
    const int lrow = lane & 15;
    const int lq   = lane >> 4;
    const int wm   = (wid >> 2) * 128;      // 2 M-waves
    const int wn   = (wid & 3) * 64;        // 4 N-waves

    // XCD n-slab mapping: x = bid&7 -> n-tiles [4x,4x+4); local covers 16m x 4n
    const int bid   = blockIdx.x;
    const int x     = bid & 7;
    const int local = bid >> 3;
    const int m_t   = (local & 7) | ((local >> 5) << 3);
    const int n_t   = x * 4 + ((local >> 3) & 3);
    const int m0 = m_t * 256;
    const int n0 = n_t * 256;

    // staging source swizzle: lane writes phys slot (lane&7) of row (+lane>>3);
    // logical slot = (lane&7) ^ (lane>>3): <4 -> hi kquad, >=4 -> lo kquad.
    const int sl = (lane & 7) ^ (lane >> 3);
    const unsigned short* asrc = (sl < 4 ? zh : zl) + (sl & 3) * 8;
    const unsigned short* bsrc = (sl < 4 ? cbh : cbl) + (sl & 3) * 8;
    const int rA = (wid << 3) + (lane >> 3);                        // A row offset
    const int rB = ((wid & 3) << 3) + ((wid >> 2) << 6) + (lane >> 3); // B row offset

#define STG_A(bf, ab, kt)                                                     \
    cp16(asrc + (size_t)(m0 + (ab) + rA) * 512 + (kt) * 32,                   \
         &As[bf][((ab) + (wid << 3)) * 64])
#define STG_B(bf, bb_, kt)                                                    \
    cp16(bsrc + (size_t)(n0 + (bb_) + rB) * 512 + (kt) * 32,                  \
         &Bs[bf][((bb_) + ((wid & 3) << 3) + ((wid >> 2) << 6)) * 64])

    f32x4 acc[8][4];
    #pragma unroll
    for (int i = 0; i < 8; ++i)
        #pragma unroll
        for (int jj = 0; jj < 4; ++jj)
            acc[i][jj] = (f32x4){0.f, 0.f, 0.f, 0.f};

    short8 a0h[4], a0l[4];   // A frag set 0 (ping)
    short8 a1h[4], a1l[4];   // A frag set 1 (pong)
    short8 fb[4];            // B frag (single buffer, hi/lo time-shared)

#define RD_A(DH, DL, bf, mh)                                                  \
    _Pragma("unroll")                                                         \
    for (int q = 0; q < 4; ++q) {                                             \
      const int rowA = wm + (mh)*64 + q*16 + lrow;                            \
      const int so = rowA*64 + (lq ^ (rowA & 7))*8;                           \
      DH[q] = *(const short8*)&As[bf][so];                                    \
      DL[q] = *(const short8*)&As[bf][so ^ 32];                               \
    }
#define RD_BH(bf)                                                             \
    _Pragma("unroll")                                                         \
    for (int p = 0; p < 4; ++p) {                                             \
      const int rowB = wn + p*16 + lrow;                                      \
      const int so = rowB*64 + (lq ^ (rowB & 7))*8;                           \
      fb[p] = *(const short8*)&Bs[bf][so];                                    \
    }
#define RD_BL(bf)                                                             \
    _Pragma("unroll")                                                         \
    for (int p = 0; p < 4; ++p) {                                             \
      const int rowB = wn + p*16 + lrow;                                      \
      const int so = (rowB*64 + (lq ^ (rowB & 7))*8) ^ 32;                    \
      fb[p] = *(const short8*)&Bs[bf][so];                                    \
    }
#define MFMA16(AR, mh)                                                        \
    _Pragma("unroll")                                                         \
    for (int q = 0; q < 4; ++q)                                               \
      _Pragma("unroll")                                                       \
      for (int p = 0; p < 4; ++p)                                             \
        acc[(mh)*4+q][p] = __builtin_amdgcn_mfma_f32_16x16x32_bf16(           \
            AR[q], fb[p], acc[(mh)*4+q][p], 0, 0, 0);

#define VM2 asm volatile("s_waitcnt vmcnt(2)" ::: "memory");
#define VM0 asm volatile("s_waitcnt vmcnt(0)" ::: "memory");

// EVEN phase (mh0): fb enters holding Bh(cur). Order: t1(Ah*Bh), prefetch
// next-A, t3(Al*Bh), fb<-Bl, t2(Ah*Bl). Leaves fb = Bl(cur).
#define PH_EVEN(VMW, STAGES, CH, CL, NH, NL, nbf, bbf)                        \
  {                                                                           \
    VMW                                                                       \
    __builtin_amdgcn_s_barrier();                                             \
    __builtin_amdgcn_sched_barrier(0);                                        \
    STAGES                                                                    \
    __builtin_amdgcn_s_setprio(1);                                            \
    MFMA16(CH, 0)                                                             \
    RD_A(NH, NL, nbf, 1)                                                      \
    MFMA16(CL, 0)                                                             \
    RD_BL(bbf)                                                                \
    MFMA16(CH, 0)                                                             \
    __builtin_amdgcn_s_setprio(0);                                            \
  }
// ODD phase (mh1): fb enters holding Bl(cur). Order: t2(Ah*Bl), prefetch
// next-A, fb<-Bh, t1(Ah*Bh), t3(Al*Bh), TAIL (fb<-Bh of next tile).
#define PH_ODD(VMW, STAGES, CH, CL, NH, NL, nbf, bbf, TAIL)                   \
  {                                                                           \
    VMW                                                                       \
    __builtin_amdgcn_s_barrier();                                             \
    __builtin_amdgcn_sched_barrier(0);                                        \
    STAGES                                                                    \
    __builtin_amdgcn_s_setprio(1);                                            \
    MFMA16(CH, 1)                                                             \
    RD_A(NH, NL, nbf, 0)                                                      \
    RD_BH(bbf)                                                                \
    MFMA16(CH, 1)                                                             \
    MFMA16(CL, 1)                                                             \
    TAIL                                                                      \
    __builtin_amdgcn_s_setprio(0);                                            \
  }

    // ---- prologue ----
    STG_A(0, 0, 0);  STG_A(0, 128, 0);
    STG_B(0, 0, 0);  STG_B(0, 128, 0); STG_B(0, 32, 0); STG_B(0, 160, 0);
    STG_A(0, 64, 0); STG_A(0, 192, 0);
    STG_A(1, 0, 1);  STG_A(1, 128, 1);
    asm volatile("s_waitcnt vmcnt(4)" ::: "memory");  // Aalpha+B landed
    __builtin_amdgcn_s_barrier();
    __builtin_amdgcn_sched_barrier(0);
    RD_A(a0h, a0l, 0, 0);
    RD_BH(0);

    #pragma unroll 1
    for (int j = 0; j < 7; ++j) {
        const int tO = 2*j + 1, tE = 2*j + 2, tN = 2*j + 3;
        PH_EVEN(VM2, { STG_B(1,0,tO); STG_B(1,128,tO); STG_B(1,32,tO); STG_B(1,160,tO);
                       STG_A(1,64,tO); STG_A(1,192,tO); },
                a0h, a0l, a1h, a1l, 0, 0)
        PH_ODD (VM2, { STG_A(0,0,tE); STG_A(0,128,tE); },
                a1h, a1l, a0h, a0l, 1, 0, RD_BH(1))
        PH_EVEN(VM2, { STG_B(0,0,tE); STG_B(0,128,tE); STG_B(0,32,tE); STG_B(0,160,tE);
                       STG_A(0,64,tE); STG_A(0,192,tE); },
                a0h, a0l, a1h, a1l, 1, 1)
        PH_ODD (VM2, { STG_A(1,0,tN); STG_A(1,128,tN); },
                a1h, a1l, a0h, a0l, 0, 1, RD_BH(0))
    }
    // ---- peeled last iteration (tiles 14=buf0, 15=buf1) ----
    PH_EVEN(VM2, { STG_B(1,0,15); STG_B(1,128,15); STG_B(1,32,15); STG_B(1,160,15);
                   STG_A(1,64,15); STG_A(1,192,15); },
            a0h, a0l, a1h, a1l, 0, 0)
    PH_ODD (VM2, {}, a1h, a1l, a0h, a0l, 1, 0, RD_BH(1))
    PH_EVEN(VM0, {}, a0h, a0l, a1h, a1l, 1, 1)
    {   // final ODD (buf1 mh1): no stages, no prefetch, no tail
        __builtin_amdgcn_s_barrier();
        __builtin_amdgcn_sched_barrier(0);
        __builtin_amdgcn_s_setprio(1);
        MFMA16(a1h, 1)
        RD_BH(1)
        MFMA16(a1h, 1)
        MFMA16(a1l, 1)
        __builtin_amdgcn_s_setprio(0);
    }

#undef PH_EVEN
#undef PH_ODD
#undef VM2
#undef VM0
#undef MFMA16
#undef RD_A
#undef RD_BH
#undef RD_BL
#undef STG_A
#undef STG_B

    const float wq = 0.5f / fmaxf(var_q[0], 1e-10f);
    #pragma unroll
    for (int nt = 0; nt < 4; ++nt) {
        const int gcol = n0 + wn + nt * 16 + lrow;
        const float cn = cnorm[gcol];
        #pragma unroll
        for (int mt = 0; mt < 8; ++mt) {
            #pragma unroll
            for (int r = 0; r < 4; ++r) {
                const int grow = m0 + wm + mt * 16 + lq * 4 + r;
                logit[(size_t)grow * KCODES + gcol] = wq * (2.0f * acc[mt][nt][r] - cn);
            }
        }
    }
}

// ---------------- K3: fused stats + colsum + encodings ----------------
// R10 (resubmit after infra failure; barrier-uniformity/OOB/VGPR audited):
// the ghi[8192] LDS buffer was a SAME-THREAD round trip (write ghi[col],
// read ghi[col] by the same thread — why it never needed a barrier).
// Removed: g_hi now lives in 16 VGPRs. Block = 512 threads (16 cols/thread,
// halved per-thread arrays), LDS 96B, __launch_bounds__(512,4) caps VGPR at
// 128 -> 16 waves/CU (was stuck at ~2 blocks/CU / 21% occupancy, measured).
// Latency-bound kernel (VALUBusy 48%, HBM 14%): occupancy is the lever.
#define PRL(rr, larr)                                                       \
  {                                                                         \
    const float* lrowp = logit + (size_t)(rr) * KCODES;                     \
    _Pragma("unroll")                                                       \
    for (int j = 0; j < 4; ++j) {                                           \
        float4 v = *(const float4*)(lrowp + t * 4 + j * 2048);              \
        larr[j*4+0] = v.x; larr[j*4+1] = v.y;                               \
        larr[j*4+2] = v.z; larr[j*4+3] = v.w;                               \
    }                                                                       \
  }

#define PRB(rr, larr, garr)                                                 \
  {                                                                         \
    float m1 = -3.0e38f, m2 = -3.0e38f;                                     \
    _Pragma("unroll")                                                       \
    for (int e = 0; e < 16; ++e) {                                          \
        m1 = fmaxf(m1, larr[e]);                                            \
        m2 = fmaxf(m2, (larr[e] + garr[e]) * 2.0f);                         \
    }                                                                       \
    red2max8(m1, m2, red);                                                  \
    float s1 = 0.f, t1 = 0.f, s2 = 0.f;                                     \
    _Pragma("unroll")                                                       \
    for (int e = 0; e < 16; ++e) {                                          \
        float xx = larr[e] - m1;                                            \
        float yy = (larr[e] + garr[e]) * 2.0f - m2;                         \
        float e1 = __expf(xx);                                              \
        float e2 = __expf(yy);                                              \
        s1 += e1; t1 += e1 * xx; s2 += e2;                                  \
        larr[e] = e1; garr[e] = e2;                                         \
    }                                                                       \
    red3sum8(s1, t1, s2, red);                                              \
    const float is1 = 1.0f / s1, is2 = 1.0f / s2;                           \
    unsigned short o16[16];                                                 \
    _Pragma("unroll")                                                       \
    for (int e = 0; e < 16; ++e) {                                          \
        csum[e] += larr[e] * is1;                                           \
        o16[e] = f2bf(garr[e] * is2);                                       \
    }                                                                       \
    unsigned short* dstp = (unsigned short*)logit + (size_t)(rr) * (2 * KCODES); \
    _Pragma("unroll")                                                       \
    for (int j = 0; j < 4; ++j)                                             \
        *(ushort4*)(dstp + t * 4 + j * 2048) = *(ushort4*)&o16[j * 4];      \
    if (t == 0) kld += t1 * is1 - __logf(s1);                               \
  }

__global__ __launch_bounds__(512, 4) void k_fused(float* __restrict__ logit,
                                                  float* __restrict__ acc) {
    __shared__ float red[24];
    const int b = blockIdx.x;       // 0..1023
    const int t = threadIdx.x;      // 0..511
    float csum[16];
    #pragma unroll
    for (int e = 0; e < 16; ++e) csum[e] = 0.f;
    float kld = 0.f;

    for (int i = 0; i < 2; ++i) {
        const int r_lo = b * 2 + i;       // < 2048
        const int r_hi = r_lo + 2048;

        float l[16], g_lo[16], g_hi[16];
        PRL(r_lo, l)                      // issue loads; hide under threefry

        #pragma unroll
        for (int j = 0; j < 4; ++j)
            #pragma unroll
            for (int e4 = 0; e4 < 4; ++e4) {
                const uint32_t col = (uint32_t)(t * 4 + j * 2048 + e4);
                const uint32_t jg  = (uint32_t)r_lo * (uint32_t)KCODES + col;
                uint32_t b0, b1;
                threefry2(jg, jg + HALF_NK, b0, b1);
                g_lo[j*4+e4] = gum(b0);
                g_hi[j*4+e4] = gum(b1);   // registers — same thread, same col
            }

        PRB(r_lo, l, g_lo)

        PRL(r_hi, l)
        PRB(r_hi, l, g_hi)
    }

    // partial colsum -> dead second halves of this block's own lo-row slots.
    // cols t*4+j*2048: j<2 -> col<4096 (slot 2b), j>=2 -> col>=4096 (slot 2b+1)
    float* pa = logit + (size_t)(2 * b) * KCODES + (KCODES / 2);
    float* pb = logit + (size_t)(2 * b + 1) * KCODES + (KCODES / 2);
    #pragma unroll
    for (int j = 0; j < 2; ++j)
        *(float4*)&pa[t * 4 + j * 2048] =
            make_float4(csum[j*4], csum[j*4+1], csum[j*4+2], csum[j*4+3]);
    #pragma unroll
    for (int j = 2; j < 4; ++j)
        *(float4*)&pb[t * 4 + (j - 2) * 2048] =
            make_float4(csum[j*4], csum[j*4+1], csum[j*4+2], csum[j*4+3]);
    if (t == 0) atomicAdd(acc + 0, kld);
}

// ---------------- K4: k_mid — gemm2 (pipelined) + colsum stage 1 ------------
// blocks [0,512):  gemm2 z_hat = enc16 @ cbT^T, tile 64x128, BK=64, ksplit 2.
//   Double-buffered LDS, STAGE(next) before compute(cur), one __syncthreads
//   per K-step (drain hidden under 16 MFMA + 12 ds_read).
// blocks [512,1024): colsum stage 1 (1024 in-logit partials -> S[16][8192]).
#define BK2 64
__global__ __launch_bounds__(256) void k_mid(const unsigned short* __restrict__ enc16,
                                             const unsigned short* __restrict__ cbT,
                                             float* __restrict__ outA,
                                             float* __restrict__ out,
                                             float* __restrict__ S) {
    __shared__ __align__(16) unsigned short AS[2][64 * BK2];    // 2 x 8 KB
    __shared__ __align__(16) unsigned short BS[2][128 * BK2];   // 2 x 16 KB
    const int b = blockIdx.x;
    const int t = threadIdx.x;

    if (b >= 512) {
        // ---- tail1 role: sum 64 partials for 256 columns ----
        const int bb2 = b - 512;
        const int g = bb2 >> 5;          // 0..15 partial-group
        const int w = bb2 & 31;          // 0..31 column window
        const int col = w * 256 + t;
        const float* logit = (const float*)enc16;
        const float* base = logit + (size_t)(col >= 4096 ? KCODES : 0)
                          + (KCODES / 2) + (col & 4095);
        float s = 0.f;
        #pragma unroll 8
        for (int bb = g * 64; bb < g * 64 + 64; ++bb)
            s += base[(size_t)bb * (2 * KCODES)];
        S[(size_t)g * KCODES + col] = s;
        return;
    }

    // ---- gemm2 role ----
    const int x   = b & 3;
    const int y   = (b >> 2) & 63;
    const int z   = b >> 8;
    const int n0  = x * 128;
    const int m0  = y * 64;
    const int kz0 = z * (KCODES / 2);
    float* dstC   = z ? out : outA;
    const int w    = t >> 6;
    const int lane = t & 63;
    const int wm   = (w >> 1) * 32;
    const int wn   = (w & 1) * 64;
    const int lrow = lane & 15;
    const int lq   = lane >> 4;
    const int srow = lane >> 3;                    // staging row 0..7 in chunk
    const int ssl  = (lane & 7) ^ (lane >> 3);     // logical slot (XOR swizzle)
    const int scol = ssl * 8;                      // pre-swizzled k-offset

    const unsigned short* Asrc = enc16 + (size_t)(m0 + srow) * (2 * KCODES) + scol;
    const unsigned short* Bsrc = cbT   + (size_t)(n0 + srow) * KCODES + scol;

#define STG2(bf, kt)                                                          \
    {                                                                         \
        _Pragma("unroll")                                                     \
        for (int j = 0; j < 2; ++j) {                                         \
            const int ja = w * 2 + j;                                         \
            cp16(Asrc + (size_t)(ja * 8) * (2 * KCODES) + (kt), &AS[bf][ja * 512]); \
        }                                                                     \
        _Pragma("unroll")                                                     \
        for (int j = 0; j < 4; ++j) {                                         \
            const int jb = w * 4 + j;                                         \
            cp16(Bsrc + (size_t)(jb * 8) * KCODES + (kt), &BS[bf][jb * 512]); \
        }                                                                     \
    }

    f32x4 acc[2][4];
    #pragma unroll
    for (int i = 0; i < 2; ++i)
        #pragma unroll
        for (int j = 0; j < 4; ++j)
            acc[i][j] = (f32x4){0.f, 0.f, 0.f, 0.f};

    // prologue: stage tile 0
    STG2(0, kz0)
    __syncthreads();           // implicit vmcnt(0) drain + barrier

    int buf = 0;
    #pragma unroll 1
    for (int kt = kz0; kt < kz0 + KCODES / 2; kt += BK2) {
        if (kt + BK2 < kz0 + KCODES / 2)
            STG2(buf ^ 1, kt + BK2)          // issue next-tile loads FIRST

        #pragma unroll
        for (int chunk = 0; chunk < 2; ++chunk) {
            short8 af[2];
            #pragma unroll
            for (int mt = 0; mt < 2; ++mt) {
                const int rowA = wm + mt * 16 + lrow;
                af[mt] = *(const short8*)&AS[buf][rowA * BK2 + ((chunk * 4 + lq) ^ (rowA & 7)) * 8];
            }
            #pragma unroll
            for (int nt = 0; nt < 4; ++nt) {
                const int rowB = wn + nt * 16 + lrow;
                const short8 bf = *(const short8*)&BS[buf][rowB * BK2 + ((chunk * 4 + lq) ^ (rowB & 7)) * 8];
                #pragma unroll
                for (int mt = 0; mt < 2; ++mt)
                    acc[mt][nt] = __builtin_amdgcn_mfma_f32_16x16x32_bf16(af[mt], bf, acc[mt][nt], 0, 0, 0);
            }
        }

        __syncthreads();       // drains this iter's stage loads (overlapped above)
        buf ^= 1;
    }
#undef STG2

    #pragma unroll
    for (int mt = 0; mt < 2; ++mt)
        #pragma unroll
        for (int nt = 0; nt < 4; ++nt)
            #pragma unroll
            for (int r = 0; r < 4; ++r) {
                const int grow = m0 + wm + mt * 16 + lq * 4 + r;
                const int gcol = n0 + wn + nt * 16 + lrow;
                dstC[(size_t)grow * DDIM + gcol] = acc[mt][nt][r];
            }
}

// ---------------- K5: tail2 (entropy from S + out-combine + cont. KLD) ------
// blocks [0,32): column entropy from S[16][8192] (16 adds per column)
// blocks [32,544): out = out + outA, accumulate (z - out)^2
__global__ __launch_bounds__(256) void k_tail2(const float* __restrict__ S,
                                               const float* __restrict__ z,
                                               const float* __restrict__ outA,
                                               float* __restrict__ out,
                                               float* __restrict__ acc) {
    __shared__ float red[4];
    const int b = blockIdx.x;
    const int t = threadIdx.x;
    if (b < 32) {
        const int col = b * 256 + t;
        float s = 0.f;
        #pragma unroll
        for (int g = 0; g < 16; ++g)
            s += S[(size_t)g * KCODES + col];
        float a = s * INV_N;
        float ent = a * __logf(a + 1e-7f);
        ent = blockReduce1(ent, red);
        if (t == 0) atomicAdd(acc + 2, ent);
    } else {
        const size_t base = (size_t)(b - 32) * 4096 + t * 4;
        float p = 0.f;
        #pragma unroll
        for (int j = 0; j < 4; ++j) {
            const size_t idx = base + j * 1024;
            float4 o1 = *(const float4*)(out + idx);
            float4 o2 = *(const float4*)(outA + idx);
            float4 zv = *(const float4*)(z + idx);
            float4 s4;
            s4.x = o1.x + o2.x; s4.y = o1.y + o2.y;
            s4.z = o1.z + o2.z; s4.w = o1.w + o2.w;
            *(float4*)(out + idx) = s4;
            float dx = zv.x - s4.x, dy = zv.y - s4.y;
            float dz = zv.z - s4.z, dw = zv.w - s4.w;
            p += dx*dx + dy*dy + dz*dz + dw*dw;
        }
        p = blockReduce1(p, red);
        if (t == 0) atomicAdd(acc + 1, p);
    }
}

// ---------------- K6: finalize ----------------
__global__ __launch_bounds__(64) void k_final(const float* __restrict__ acc,
                                              const float* __restrict__ var_q,
                                              float* __restrict__ out) {
    if (threadIdx.x == 0) {
        float w = 0.5f / fmaxf(var_q[0], 1e-10f);
        float loss = acc[0] / BS_F + acc[1] * w / BS_F;
        out[(size_t)N_ROWS * DDIM]     = loss;
        out[(size_t)N_ROWS * DDIM + 1] = expf(-acc[2]);
    }
}

// ---------------- launch ----------------
extern "C" void kernel_launch(void* const* d_in, const int* in_sizes, int n_in,
                              void* d_out, int out_size, void* d_ws, size_t ws_size,
                              hipStream_t stream) {
    const float* z     = (const float*)d_in[0];
    const float* var_q = (const float*)d_in[1];
    const float* cb    = (const float*)d_in[2];
    float* out = (float*)d_out;
    float* ws  = (float*)d_ws;
    if (ws_size < (size_t)WS_FLOATS * sizeof(float)) return;  // need ~168 MB

    float* logit  = ws + OFF_LOGIT;
    float* cnorm  = ws + OFF_CNORM;
    float* accp   = ws + OFF_ACC;
    unsigned short* zh  = (unsigned short*)(ws + OFF_ZH);
    unsigned short* zl  = (unsigned short*)(ws + OFF_ZL);
    unsigned short* cbh = (unsigned short*)(ws + OFF_CBH);
    unsigned short* cbl = (unsigned short*)(ws + OFF_CBL);
    unsigned short* cbT = (unsigned short*)(ws + OFF_CBT);
    float* outA = ws + OFF_CBL;   // cbl reused after gemm1 (8MB)
    float* S    = ws + OFF_ZH;    // zh reused after gemm1 (512KB of 4MB)

    k_prep  <<<4097, 256, 0, stream>>>(z, cb, zh, zl, cbh, cbl, cbT, cnorm, accp);
    k_gemm1 <<<512, 512, 0, stream>>>(zh, zl, cbh, cbl, cnorm, var_q, logit);
    k_fused <<<1024, 512, 0, stream>>>(logit, accp);
    k_mid   <<<1024, 256, 0, stream>>>((const unsigned short*)logit, cbT, outA, out, S);
    k_tail2 <<<544, 256, 0, stream>>>(S, z, outA, out, accp);
    k_final <<<1, 64, 0, stream>>>(accp, var_q, out);
}

// Round 12
// 333.951 us; speedup vs baseline: 1.0779x; 1.0597x over previous
//
#include <hip/hip_runtime.h>
#include <stdint.h>

// ---------------- problem constants ----------------
#define N_ROWS 4096      // bs*seq = 8*512
#define DDIM   512
#define KCODES 8192
#define NK     (N_ROWS * KCODES)   // 33,554,432
#define HALF_NK 16777216u
#define BS_F   8.0f
#define INV_N  (1.0f / 4096.0f)

// ---------------- ws layout (float offsets) ----------------
// logit region (NK floats): row n's 32KB slot holds (after k_fused)
//   [0,16KB):  bf16 encodings for row n  (read by k_mid gemm2-role)
//   [16KB,32KB): for slots n<2048: colsum partial fragment (read by k_mid tail1-role)
// part[b][c] (b<1024): c<4096 -> slot 2b second half; c>=4096 -> slot 2b+1.
// zh region (dead after gemm1) hosts S[16][8192] second-level colsums (512KB).
// cbl (8MB) reused as outA (gemm2 k-split partial 0) after gemm1.
#define OFF_LOGIT   0
#define OFF_CNORM   (NK)
#define OFF_ACC     (OFF_CNORM + KCODES)   // [0]=sum p*logp, [1]=sum (z-zhat)^2, [2]=entropy
#define OFF_ZH      (OFF_ACC + 4)                    // bf16 z hi  [4096*512]
#define OFF_ZL      (OFF_ZH + (N_ROWS*DDIM/2))       // bf16 z lo
#define OFF_CBH     (OFF_ZL + (N_ROWS*DDIM/2))       // bf16 cb hi [8192*512]
#define OFF_CBL     (OFF_CBH + (KCODES*DDIM/2))      // bf16 cb lo
#define OFF_CBT     (OFF_CBL + (KCODES*DDIM/2))      // bf16 cb^T  [512*8192]
#define WS_FLOATS   (OFF_CBT + (DDIM*KCODES/2))      // ~168MB

typedef __attribute__((ext_vector_type(8))) short short8;
typedef __attribute__((ext_vector_type(4))) float f32x4;

__device__ __forceinline__ unsigned short f2bf(float x) {
    uint32_t u = __float_as_uint(x);
    u += 0x7fffu + ((u >> 16) & 1u);
    return (unsigned short)(u >> 16);
}

// async global->LDS, 16B per lane; lds base must be wave-uniform,
// lane i lands at lds + i*16 (no padding allowed in the chunk).
__device__ __forceinline__ void cp16(const unsigned short* g, unsigned short* l) {
    __builtin_amdgcn_global_load_lds(
        (const __attribute__((address_space(1))) void*)g,
        (__attribute__((address_space(3))) void*)l, 16, 0, 0);
}

// ---------------- JAX threefry2x32-20, key(42) = (0,42) ----------------
__device__ __forceinline__ uint32_t rotl32(uint32_t x, int r) {
    return (x << r) | (x >> (32 - r));
}

__device__ __forceinline__ void threefry2(uint32_t c0, uint32_t c1,
                                          uint32_t& o0, uint32_t& o1) {
    const uint32_t ks0 = 0u, ks1 = 42u, ks2 = 0x1BD11BDAu ^ 0u ^ 42u;
    uint32_t x0 = c0 + ks0;
    uint32_t x1 = c1 + ks1;
#define TF_R(r) { x0 += x1; x1 = rotl32(x1, r); x1 ^= x0; }
    TF_R(13) TF_R(15) TF_R(26) TF_R(6)
    x0 += ks1; x1 += ks2 + 1u;
    TF_R(17) TF_R(29) TF_R(16) TF_R(24)
    x0 += ks2; x1 += ks0 + 2u;
    TF_R(13) TF_R(15) TF_R(26) TF_R(6)
    x0 += ks0; x1 += ks1 + 3u;
    TF_R(17) TF_R(29) TF_R(16) TF_R(24)
    x0 += ks1; x1 += ks2 + 4u;
    TF_R(13) TF_R(15) TF_R(26) TF_R(6)
    x0 += ks2; x1 += ks0 + 5u;
#undef TF_R
    o0 = x0; o1 = x1;
}

__device__ __forceinline__ float u01(uint32_t bits) {
    return __uint_as_float((bits >> 9) | 0x3f800000u) - 1.0f;
}

__device__ __forceinline__ float gum(uint32_t bits) {
    float u = u01(bits);
    return -__logf(-__logf(u + 1e-10f) + 1e-10f);
}

// ---------------- block reduce helpers (256 threads = 4 waves) ----------------
__device__ __forceinline__ float blockReduce1(float v, float* red) {
    #pragma unroll
    for (int o = 32; o > 0; o >>= 1) v += __shfl_down(v, o);
    __syncthreads();
    if ((threadIdx.x & 63) == 0) red[threadIdx.x >> 6] = v;
    __syncthreads();
    return red[0] + red[1] + red[2] + red[3];
}

// ---------------- block reduce helpers (512 threads = 8 waves) ----------------
__device__ __forceinline__ void red2max8(float& a, float& b, float* red) {
    #pragma unroll
    for (int o = 32; o > 0; o >>= 1) {
        a = fmaxf(a, __shfl_down(a, o));
        b = fmaxf(b, __shfl_down(b, o));
    }
    __syncthreads();
    if ((threadIdx.x & 63) == 0) {
        red[(threadIdx.x >> 6) * 2 + 0] = a;
        red[(threadIdx.x >> 6) * 2 + 1] = b;
    }
    __syncthreads();
    float a0 = fmaxf(fmaxf(red[0], red[2]), fmaxf(red[4], red[6]));
    float a1 = fmaxf(fmaxf(red[8], red[10]), fmaxf(red[12], red[14]));
    a = fmaxf(a0, a1);
    float b0 = fmaxf(fmaxf(red[1], red[3]), fmaxf(red[5], red[7]));
    float b1 = fmaxf(fmaxf(red[9], red[11]), fmaxf(red[13], red[15]));
    b = fmaxf(b0, b1);
}

__device__ __forceinline__ void red3sum8(float& a, float& b, float& c, float* red) {
    #pragma unroll
    for (int o = 32; o > 0; o >>= 1) {
        a += __shfl_down(a, o);
        b += __shfl_down(b, o);
        c += __shfl_down(c, o);
    }
    __syncthreads();
    if ((threadIdx.x & 63) == 0) {
        red[(threadIdx.x >> 6) * 3 + 0] = a;
        red[(threadIdx.x >> 6) * 3 + 1] = b;
        red[(threadIdx.x >> 6) * 3 + 2] = c;
    }
    __syncthreads();
    a = ((red[0] + red[3]) + (red[6] + red[9]))
      + ((red[12] + red[15]) + (red[18] + red[21]));
    b = ((red[1] + red[4]) + (red[7] + red[10]))
      + ((red[13] + red[16]) + (red[19] + red[22]));
    c = ((red[2] + red[5]) + (red[8] + red[11]))
      + ((red[14] + red[17]) + (red[20] + red[23]));
}

// ---------------- K1: fused prep ----------------
__global__ __launch_bounds__(256) void k_prep(const float* __restrict__ z,
                                              const float* __restrict__ cb,
                                              unsigned short* __restrict__ zh,
                                              unsigned short* __restrict__ zl,
                                              unsigned short* __restrict__ cbh,
                                              unsigned short* __restrict__ cbl,
                                              unsigned short* __restrict__ cbT,
                                              float* __restrict__ cnorm,
                                              float* __restrict__ accp) {
    __shared__ unsigned short TT[64][65];
    const int b = blockIdx.x;
    const int t = threadIdx.x;
    if (b < 3072) {
        const bool isz = (b < 1024);
        const int bb = isz ? b : b - 1024;
        const float* src = isz ? z : cb;
        unsigned short* hi = isz ? zh : cbh;
        unsigned short* lo = isz ? zl : cbl;
        const size_t idx = ((size_t)bb * 256 + t) * 8;
        float4 a = *(const float4*)(src + idx);
        float4 bv = *(const float4*)(src + idx + 4);
        float f[8] = {a.x, a.y, a.z, a.w, bv.x, bv.y, bv.z, bv.w};
        unsigned short h8[8], l8[8];
        float s = 0.f;
        #pragma unroll
        for (int e = 0; e < 8; ++e) {
            unsigned short h = f2bf(f[e]);
            float hf = __uint_as_float((uint32_t)h << 16);
            h8[e] = h;
            l8[e] = f2bf(f[e] - hf);
            s += f[e] * f[e];
        }
        *(short8*)(hi + idx) = *(short8*)h8;
        *(short8*)(lo + idx) = *(short8*)l8;
        if (!isz) {
            #pragma unroll
            for (int o = 32; o > 0; o >>= 1) s += __shfl_down(s, o);
            if ((t & 63) == 0) cnorm[bb * 4 + (t >> 6)] = s;
        }
    } else if (b < 4096) {
        const int b3 = b - 3072;
        const int k0 = (b3 & 127) * 64;
        const int d0 = (b3 >> 7) * 64;
        #pragma unroll
        for (int j = 0; j < 4; ++j) {
            const int unit = t + j * 256;
            const int r = unit >> 4;
            const int s4 = unit & 15;
            float4 v = *(const float4*)(cb + (size_t)(k0 + r) * DDIM + d0 + s4 * 4);
            TT[r][s4*4+0] = f2bf(v.x); TT[r][s4*4+1] = f2bf(v.y);
            TT[r][s4*4+2] = f2bf(v.z); TT[r][s4*4+3] = f2bf(v.w);
        }
        __syncthreads();
        #pragma unroll
        for (int j = 0; j < 2; ++j) {
            const int unit = t + j * 256;
            const int dr = unit >> 3;
            const int ks = (unit & 7) * 8;
            unsigned short o8[8];
            #pragma unroll
            for (int i = 0; i < 8; ++i) o8[i] = TT[ks + i][dr];
            *(short8*)(cbT + (size_t)(d0 + dr) * KCODES + k0 + ks) = *(short8*)o8;
        }
    } else {
        if (t < 4) accp[t] = 0.f;
    }
}

// ---------------- K2: GEMM1 — 256x256, 8 waves, prefetch-into-MFMA ----------
// Best-measured form (R3/R7: 112.6us, MfmaUtil 38.5, 915 TF = the known
// m97-structure plateau). R8's 8-phase quadrant schedule measured WORSE
// (120us). Parked permanently; scheduling probes exhausted (R2/R3/R8).
__global__ __launch_bounds__(512, 2)
void k_gemm1(const unsigned short* __restrict__ zh,
             const unsigned short* __restrict__ zl,
             const unsigned short* __restrict__ cbh,
             const unsigned short* __restrict__ cbl,
             const float* __restrict__ cnorm,
             const float* __restrict__ var_q,
             float* __restrict__ logit) {
    __shared__ __align__(1024) unsigned short As[2][256 * 64];   // 2 x 32KB
    __shared__ __align__(1024) unsigned short Bs[2][256 * 64];   // 2 x 32KB

    const int t    = threadIdx.x;           // 0..511
    const int wid  = t >> 6;                // 0..7
    const int lane = t & 63;
    const int lrow = lane & 15;
    const int lq   = lane >> 4;
    const int wm   = (wid >> 2) * 128;      // 2 M-waves
    const int wn   = (wid & 3) * 64;        // 4 N-waves

    // XCD n-slab mapping: x = bid&7 -> n-tiles [4x,4x+4); local covers 16m x 4n
    const int bid   = blockIdx.x;
    const int x     = bid & 7;
    const int local = bid >> 3;
    const int m_t   = (local & 7) | ((local >> 5) << 3);
    const int n_t   = x * 4 + ((local >> 3) & 3);
    const int m0 = m_t * 256;
    const int n0 = n_t * 256;

    // staging source swizzle: lane writes phys slot (lane&7) of row (+lane>>3);
    // logical slot = (lane&7) ^ (lane>>3): <4 -> hi kquad, >=4 -> lo kquad.
    const int sl = (lane & 7) ^ (lane >> 3);
    const unsigned short* asrc = (sl < 4 ? zh : zl) + (sl & 3) * 8;
    const unsigned short* bsrc = (sl < 4 ? cbh : cbl) + (sl & 3) * 8;
    const int rA = (wid << 3) + (lane >> 3);                        // A row offset
    const int rB = ((wid & 3) << 3) + ((wid >> 2) << 6) + (lane >> 3); // B row offset

#define STG_A(bf, ab, kt)                                                     \
    cp16(asrc + (size_t)(m0 + (ab) + rA) * 512 + (kt) * 32,                   \
         &As[bf][((ab) + (wid << 3)) * 64])
#define STG_B(bf, bb_, kt)                                                    \
    cp16(bsrc + (size_t)(n0 + (bb_) + rB) * 512 + (kt) * 32,                  \
         &Bs[bf][((bb_) + ((wid & 3) << 3) + ((wid >> 2) << 6)) * 64])

    f32x4 acc[8][4];
    #pragma unroll
    for (int i = 0; i < 8; ++i)
        #pragma unroll
        for (int jj = 0; jj < 4; ++jj)
            acc[i][jj] = (f32x4){0.f, 0.f, 0.f, 0.f};

    short8 a0h[4], a0l[4];   // A frag set 0 (ping)
    short8 a1h[4], a1l[4];   // A frag set 1 (pong)
    short8 fb[4];            // B frag (single buffer, hi/lo time-shared)

#define RD_A(DH, DL, bf, mh)                                                  \
    _Pragma("unroll")                                                         \
    for (int q = 0; q < 4; ++q) {                                             \
      const int rowA = wm + (mh)*64 + q*16 + lrow;                            \
      const int so = rowA*64 + (lq ^ (rowA & 7))*8;                           \
      DH[q] = *(const short8*)&As[bf][so];                                    \
      DL[q] = *(const short8*)&As[bf][so ^ 32];                               \
    }
#define RD_BH(bf)                                                             \
    _Pragma("unroll")                                                         \
    for (int p = 0; p < 4; ++p) {                                             \
      const int rowB = wn + p*16 + lrow;                                      \
      const int so = rowB*64 + (lq ^ (rowB & 7))*8;                           \
      fb[p] = *(const short8*)&Bs[bf][so];                                    \
    }
#define RD_BL(bf)                                                             \
    _Pragma("unroll")                                                         \
    for (int p = 0; p < 4; ++p) {                                             \
      const int rowB = wn + p*16 + lrow;                                      \
      const int so = (rowB*64 + (lq ^ (rowB & 7))*8) ^ 32;                    \
      fb[p] = *(const short8*)&Bs[bf][so];                                    \
    }
#define MFMA16(AR, mh)                                                        \
    _Pragma("unroll")                                                         \
    for (int q = 0; q < 4; ++q)                                               \
      _Pragma("unroll")                                                       \
      for (int p = 0; p < 4; ++p)                                             \
        acc[(mh)*4+q][p] = __builtin_amdgcn_mfma_f32_16x16x32_bf16(           \
            AR[q], fb[p], acc[(mh)*4+q][p], 0, 0, 0);

#define VM2 asm volatile("s_waitcnt vmcnt(2)" ::: "memory");
#define VM0 asm volatile("s_waitcnt vmcnt(0)" ::: "memory");

// EVEN phase (mh0): fb enters holding Bh(cur). Order: t1(Ah*Bh), prefetch
// next-A, t3(Al*Bh), fb<-Bl, t2(Ah*Bl). Leaves fb = Bl(cur).
#define PH_EVEN(VMW, STAGES, CH, CL, NH, NL, nbf, bbf)                        \
  {                                                                           \
    VMW                                                                       \
    __builtin_amdgcn_s_barrier();                                             \
    __builtin_amdgcn_sched_barrier(0);                                        \
    STAGES                                                                    \
    __builtin_amdgcn_s_setprio(1);                                            \
    MFMA16(CH, 0)                                                             \
    RD_A(NH, NL, nbf, 1)                                                      \
    MFMA16(CL, 0)                                                             \
    RD_BL(bbf)                                                                \
    MFMA16(CH, 0)                                                             \
    __builtin_amdgcn_s_setprio(0);                                            \
  }
// ODD phase (mh1): fb enters holding Bl(cur). Order: t2(Ah*Bl), prefetch
// next-A, fb<-Bh, t1(Ah*Bh), t3(Al*Bh), TAIL (fb<-Bh of next tile).
#define PH_ODD(VMW, STAGES, CH, CL, NH, NL, nbf, bbf, TAIL)                   \
  {                                                                           \
    VMW                                                                       \
    __builtin_amdgcn_s_barrier();                                             \
    __builtin_amdgcn_sched_barrier(0);                                        \
    STAGES                                                                    \
    __builtin_amdgcn_s_setprio(1);                                            \
    MFMA16(CH, 1)                                                             \
    RD_A(NH, NL, nbf, 0)                                                      \
    RD_BH(bbf)                                                                \
    MFMA16(CH, 1)                                                             \
    MFMA16(CL, 1)                                                             \
    TAIL                                                                      \
    __builtin_amdgcn_s_setprio(0);                                            \
  }

    // ---- prologue ----
    STG_A(0, 0, 0);  STG_A(0, 128, 0);
    STG_B(0, 0, 0);  STG_B(0, 128, 0); STG_B(0, 32, 0); STG_B(0, 160, 0);
    STG_A(0, 64, 0); STG_A(0, 192, 0);
    STG_A(1, 0, 1);  STG_A(1, 128, 1);
    asm volatile("s_waitcnt vmcnt(4)" ::: "memory");  // Aalpha+B landed
    __builtin_amdgcn_s_barrier();
    __builtin_amdgcn_sched_barrier(0);
    RD_A(a0h, a0l, 0, 0);
    RD_BH(0);

    #pragma unroll 1
    for (int j = 0; j < 7; ++j) {
        const int tO = 2*j + 1, tE = 2*j + 2, tN = 2*j + 3;
        PH_EVEN(VM2, { STG_B(1,0,tO); STG_B(1,128,tO); STG_B(1,32,tO); STG_B(1,160,tO);
                       STG_A(1,64,tO); STG_A(1,192,tO); },
                a0h, a0l, a1h, a1l, 0, 0)
        PH_ODD (VM2, { STG_A(0,0,tE); STG_A(0,128,tE); },
                a1h, a1l, a0h, a0l, 1, 0, RD_BH(1))
        PH_EVEN(VM2, { STG_B(0,0,tE); STG_B(0,128,tE); STG_B(0,32,tE); STG_B(0,160,tE);
                       STG_A(0,64,tE); STG_A(0,192,tE); },
                a0h, a0l, a1h, a1l, 1, 1)
        PH_ODD (VM2, { STG_A(1,0,tN); STG_A(1,128,tN); },
                a1h, a1l, a0h, a0l, 0, 1, RD_BH(0))
    }
    // ---- peeled last iteration (tiles 14=buf0, 15=buf1) ----
    PH_EVEN(VM2, { STG_B(1,0,15); STG_B(1,128,15); STG_B(1,32,15); STG_B(1,160,15);
                   STG_A(1,64,15); STG_A(1,192,15); },
            a0h, a0l, a1h, a1l, 0, 0)
    PH_ODD (VM2, {}, a1h, a1l, a0h, a0l, 1, 0, RD_BH(1))
    PH_EVEN(VM0, {}, a0h, a0l, a1h, a1l, 1, 1)
    {   // final ODD (buf1 mh1): no stages, no prefetch, no tail
        __builtin_amdgcn_s_barrier();
        __builtin_amdgcn_sched_barrier(0);
        __builtin_amdgcn_s_setprio(1);
        MFMA16(a1h, 1)
        RD_BH(1)
        MFMA16(a1h, 1)
        MFMA16(a1l, 1)
        __builtin_amdgcn_s_setprio(0);
    }

#undef PH_EVEN
#undef PH_ODD
#undef VM2
#undef VM0
#undef MFMA16
#undef RD_A
#undef RD_BH
#undef RD_BL
#undef STG_A
#undef STG_B

    const float wq = 0.5f / fmaxf(var_q[0], 1e-10f);
    #pragma unroll
    for (int nt = 0; nt < 4; ++nt) {
        const int gcol = n0 + wn + nt * 16 + lrow;
        const float cn = cnorm[gcol];
        #pragma unroll
        for (int mt = 0; mt < 8; ++mt) {
            #pragma unroll
            for (int r = 0; r < 4; ++r) {
                const int grow = m0 + wm + mt * 16 + lq * 4 + r;
                logit[(size_t)grow * KCODES + gcol] = wq * (2.0f * acc[mt][nt][r] - cn);
            }
        }
    }
}

// ---------------- K3: fused stats + colsum + encodings ----------------
// 512 threads, g_hi in VGPRs (the old ghi[8192] LDS was a same-thread round
// trip), LDS 96B, __launch_bounds__(512,4). Best-measured form (R11).
#define PRL(rr, larr)                                                       \
  {                                                                         \
    const float* lrowp = logit + (size_t)(rr) * KCODES;                     \
    _Pragma("unroll")                                                       \
    for (int j = 0; j < 4; ++j) {                                           \
        float4 v = *(const float4*)(lrowp + t * 4 + j * 2048);              \
        larr[j*4+0] = v.x; larr[j*4+1] = v.y;                               \
        larr[j*4+2] = v.z; larr[j*4+3] = v.w;                               \
    }                                                                       \
  }

#define PRB(rr, larr, garr)                                                 \
  {                                                                         \
    float m1 = -3.0e38f, m2 = -3.0e38f;                                     \
    _Pragma("unroll")                                                       \
    for (int e = 0; e < 16; ++e) {                                          \
        m1 = fmaxf(m1, larr[e]);                                            \
        m2 = fmaxf(m2, (larr[e] + garr[e]) * 2.0f);                         \
    }                                                                       \
    red2max8(m1, m2, red);                                                  \
    float s1 = 0.f, t1 = 0.f, s2 = 0.f;                                     \
    _Pragma("unroll")                                                       \
    for (int e = 0; e < 16; ++e) {                                          \
        float xx = larr[e] - m1;                                            \
        float yy = (larr[e] + garr[e]) * 2.0f - m2;                         \
        float e1 = __expf(xx);                                              \
        float e2 = __expf(yy);                                              \
        s1 += e1; t1 += e1 * xx; s2 += e2;                                  \
        larr[e] = e1; garr[e] = e2;                                         \
    }                                                                       \
    red3sum8(s1, t1, s2, red);                                              \
    const float is1 = 1.0f / s1, is2 = 1.0f / s2;                           \
    unsigned short o16[16];                                                 \
    _Pragma("unroll")                                                       \
    for (int e = 0; e < 16; ++e) {                                          \
        csum[e] += larr[e] * is1;                                           \
        o16[e] = f2bf(garr[e] * is2);                                       \
    }                                                                       \
    unsigned short* dstp = (unsigned short*)logit + (size_t)(rr) * (2 * KCODES); \
    _Pragma("unroll")                                                       \
    for (int j = 0; j < 4; ++j)                                             \
        *(ushort4*)(dstp + t * 4 + j * 2048) = *(ushort4*)&o16[j * 4];      \
    if (t == 0) kld += t1 * is1 - __logf(s1);                               \
  }

__global__ __launch_bounds__(512, 4) void k_fused(float* __restrict__ logit,
                                                  float* __restrict__ acc) {
    __shared__ float red[24];
    const int b = blockIdx.x;       // 0..1023
    const int t = threadIdx.x;      // 0..511
    float csum[16];
    #pragma unroll
    for (int e = 0; e < 16; ++e) csum[e] = 0.f;
    float kld = 0.f;

    for (int i = 0; i < 2; ++i) {
        const int r_lo = b * 2 + i;       // < 2048
        const int r_hi = r_lo + 2048;

        float l[16], g_lo[16], g_hi[16];
        PRL(r_lo, l)                      // issue loads; hide under threefry

        #pragma unroll
        for (int j = 0; j < 4; ++j)
            #pragma unroll
            for (int e4 = 0; e4 < 4; ++e4) {
                const uint32_t col = (uint32_t)(t * 4 + j * 2048 + e4);
                const uint32_t jg  = (uint32_t)r_lo * (uint32_t)KCODES + col;
                uint32_t b0, b1;
                threefry2(jg, jg + HALF_NK, b0, b1);
                g_lo[j*4+e4] = gum(b0);
                g_hi[j*4+e4] = gum(b1);   // registers — same thread, same col
            }

        PRB(r_lo, l, g_lo)

        PRL(r_hi, l)
        PRB(r_hi, l, g_hi)
    }

    // partial colsum -> dead second halves of this block's own lo-row slots.
    // cols t*4+j*2048: j<2 -> col<4096 (slot 2b), j>=2 -> col>=4096 (slot 2b+1)
    float* pa = logit + (size_t)(2 * b) * KCODES + (KCODES / 2);
    float* pb = logit + (size_t)(2 * b + 1) * KCODES + (KCODES / 2);
    #pragma unroll
    for (int j = 0; j < 2; ++j)
        *(float4*)&pa[t * 4 + j * 2048] =
            make_float4(csum[j*4], csum[j*4+1], csum[j*4+2], csum[j*4+3]);
    #pragma unroll
    for (int j = 2; j < 4; ++j)
        *(float4*)&pb[t * 4 + (j - 2) * 2048] =
            make_float4(csum[j*4], csum[j*4+1], csum[j*4+2], csum[j*4+3]);
    if (t == 0) atomicAdd(acc + 0, kld);
}

// ---------------- K4: k_mid — gemm2 (pipelined) + colsum stage 1 ------------
// blocks [0,512):  gemm2 z_hat = enc16 @ cbT^T, tile 64x128, BK=64, ksplit 2.
//   R12: XCD-bijective remap — the 4 n-blocks (x) sharing a (y,z) A-panel now
//   sit at consecutive s on the SAME XCD (xcd=b&7, s=b>>3; y=xcd+8*(s>>3),
//   x=s&3, z=(s>>2)&1; verified bijective over [0,512)). A-panel (512KB) is
//   fetched once per (y,z) and shared via that XCD's L2; B (16MB unique, 64x
//   reuse) falls to L3. R5 counters showed FETCH=174MB vs 112MB unique — the
//   old b=x+4y linearization spread A-partners across 4 XCDs.
// blocks [512,1024): colsum stage 1 (1024 in-logit partials -> S[16][8192]).
#define BK2 64
__global__ __launch_bounds__(256) void k_mid(const unsigned short* __restrict__ enc16,
                                             const unsigned short* __restrict__ cbT,
                                             float* __restrict__ outA,
                                             float* __restrict__ out,
                                             float* __restrict__ S) {
    __shared__ __align__(16) unsigned short AS[2][64 * BK2];    // 2 x 8 KB
    __shared__ __align__(16) unsigned short BS[2][128 * BK2];   // 2 x 16 KB
    const int b = blockIdx.x;
    const int t = threadIdx.x;

    if (b >= 512) {
        // ---- tail1 role: sum 64 partials for 256 columns ----
        const int bb2 = b - 512;
        const int g = bb2 >> 5;          // 0..15 partial-group
        const int w = bb2 & 31;          // 0..31 column window
        const int col = w * 256 + t;
        const float* logit = (const float*)enc16;
        const float* base = logit + (size_t)(col >= 4096 ? KCODES : 0)
                          + (KCODES / 2) + (col & 4095);
        float s = 0.f;
        #pragma unroll 8
        for (int bb = g * 64; bb < g * 64 + 64; ++bb)
            s += base[(size_t)bb * (2 * KCODES)];
        S[(size_t)g * KCODES + col] = s;
        return;
    }

    // ---- gemm2 role (XCD-bijective decode) ----
    const int xcd = b & 7;
    const int sq  = b >> 3;                 // 0..63 within XCD
    const int y   = xcd + ((sq >> 3) << 3); // 8 y-values per XCD
    const int x   = sq & 3;                 // n-partner, fastest (shares A via L2)
    const int z   = (sq >> 2) & 1;
    const int n0  = x * 128;
    const int m0  = y * 64;
    const int kz0 = z * (KCODES / 2);
    float* dstC   = z ? out : outA;
    const int w    = t >> 6;
    const int lane = t & 63;
    const int wm   = (w >> 1) * 32;
    const int wn   = (w & 1) * 64;
    const int lrow = lane & 15;
    const int lq   = lane >> 4;
    const int srow = lane >> 3;                    // staging row 0..7 in chunk
    const int ssl  = (lane & 7) ^ (lane >> 3);     // logical slot (XOR swizzle)
    const int scol = ssl * 8;                      // pre-swizzled k-offset

    const unsigned short* Asrc = enc16 + (size_t)(m0 + srow) * (2 * KCODES) + scol;
    const unsigned short* Bsrc = cbT   + (size_t)(n0 + srow) * KCODES + scol;

#define STG2(bf, kt)                                                          \
    {                                                                         \
        _Pragma("unroll")                                                     \
        for (int j = 0; j < 2; ++j) {                                         \
            const int ja = w * 2 + j;                                         \
            cp16(Asrc + (size_t)(ja * 8) * (2 * KCODES) + (kt), &AS[bf][ja * 512]); \
        }                                                                     \
        _Pragma("unroll")                                                     \
        for (int j = 0; j < 4; ++j) {                                         \
            const int jb = w * 4 + j;                                         \
            cp16(Bsrc + (size_t)(jb * 8) * KCODES + (kt), &BS[bf][jb * 512]); \
        }                                                                     \
    }

    f32x4 acc[2][4];
    #pragma unroll
    for (int i = 0; i < 2; ++i)
        #pragma unroll
        for (int j = 0; j < 4; ++j)
            acc[i][j] = (f32x4){0.f, 0.f, 0.f, 0.f};

    // prologue: stage tile 0
    STG2(0, kz0)
    __syncthreads();           // implicit vmcnt(0) drain + barrier

    int buf = 0;
    #pragma unroll 1
    for (int kt = kz0; kt < kz0 + KCODES / 2; kt += BK2) {
        if (kt + BK2 < kz0 + KCODES / 2)
            STG2(buf ^ 1, kt + BK2)          // issue next-tile loads FIRST

        #pragma unroll
        for (int chunk = 0; chunk < 2; ++chunk) {
            short8 af[2];
            #pragma unroll
            for (int mt = 0; mt < 2; ++mt) {
                const int rowA = wm + mt * 16 + lrow;
                af[mt] = *(const short8*)&AS[buf][rowA * BK2 + ((chunk * 4 + lq) ^ (rowA & 7)) * 8];
            }
            #pragma unroll
            for (int nt = 0; nt < 4; ++nt) {
                const int rowB = wn + nt * 16 + lrow;
                const short8 bf = *(const short8*)&BS[buf][rowB * BK2 + ((chunk * 4 + lq) ^ (rowB & 7)) * 8];
                #pragma unroll
                for (int mt = 0; mt < 2; ++mt)
                    acc[mt][nt] = __builtin_amdgcn_mfma_f32_16x16x32_bf16(af[mt], bf, acc[mt][nt], 0, 0, 0);
            }
        }

        __syncthreads();       // drains this iter's stage loads (overlapped above)
        buf ^= 1;
    }
#undef STG2

    #pragma unroll
    for (int mt = 0; mt < 2; ++mt)
        #pragma unroll
        for (int nt = 0; nt < 4; ++nt)
            #pragma unroll
            for (int r = 0; r < 4; ++r) {
                const int grow = m0 + wm + mt * 16 + lq * 4 + r;
                const int gcol = n0 + wn + nt * 16 + lrow;
                dstC[(size_t)grow * DDIM + gcol] = acc[mt][nt][r];
            }
}

// ---------------- K5: tail2 (entropy from S + out-combine + cont. KLD) ------
// blocks [0,32): column entropy from S[16][8192] (16 adds per column)
// blocks [32,544): out = out + outA, accumulate (z - out)^2
__global__ __launch_bounds__(256) void k_tail2(const float* __restrict__ S,
                                               const float* __restrict__ z,
                                               const float* __restrict__ outA,
                                               float* __restrict__ out,
                                               float* __restrict__ acc) {
    __shared__ float red[4];
    const int b = blockIdx.x;
    const int t = threadIdx.x;
    if (b < 32) {
        const int col = b * 256 + t;
        float s = 0.f;
        #pragma unroll
        for (int g = 0; g < 16; ++g)
            s += S[(size_t)g * KCODES + col];
        float a = s * INV_N;
        float ent = a * __logf(a + 1e-7f);
        ent = blockReduce1(ent, red);
        if (t == 0) atomicAdd(acc + 2, ent);
    } else {
        const size_t base = (size_t)(b - 32) * 4096 + t * 4;
        float p = 0.f;
        #pragma unroll
        for (int j = 0; j < 4; ++j) {
            const size_t idx = base + j * 1024;
            float4 o1 = *(const float4*)(out + idx);
            float4 o2 = *(const float4*)(outA + idx);
            float4 zv = *(const float4*)(z + idx);
            float4 s4;
            s4.x = o1.x + o2.x; s4.y = o1.y + o2.y;
            s4.z = o1.z + o2.z; s4.w = o1.w + o2.w;
            *(float4*)(out + idx) = s4;
            float dx = zv.x - s4.x, dy = zv.y - s4.y;
            float dz = zv.z - s4.z, dw = zv.w - s4.w;
            p += dx*dx + dy*dy + dz*dz + dw*dw;
        }
        p = blockReduce1(p, red);
        if (t == 0) atomicAdd(acc + 1, p);
    }
}

// ---------------- K6: finalize ----------------
__global__ __launch_bounds__(64) void k_final(const float* __restrict__ acc,
                                              const float* __restrict__ var_q,
                                              float* __restrict__ out) {
    if (threadIdx.x == 0) {
        float w = 0.5f / fmaxf(var_q[0], 1e-10f);
        float loss = acc[0] / BS_F + acc[1] * w / BS_F;
        out[(size_t)N_ROWS * DDIM]     = loss;
        out[(size_t)N_ROWS * DDIM + 1] = expf(-acc[2]);
    }
}

// ---------------- launch ----------------
extern "C" void kernel_launch(void* const* d_in, const int* in_sizes, int n_in,
                              void* d_out, int out_size, void* d_ws, size_t ws_size,
                              hipStream_t stream) {
    const float* z     = (const float*)d_in[0];
    const float* var_q = (const float*)d_in[1];
    const float* cb    = (const float*)d_in[2];
    float* out = (float*)d_out;
    float* ws  = (float*)d_ws;
    if (ws_size < (size_t)WS_FLOATS * sizeof(float)) return;  // need ~168 MB

    float* logit  = ws + OFF_LOGIT;
    float* cnorm  = ws + OFF_CNORM;
    float* accp   = ws + OFF_ACC;
    unsigned short* zh  = (unsigned short*)(ws + OFF_ZH);
    unsigned short* zl  = (unsigned short*)(ws + OFF_ZL);
    unsigned short* cbh = (unsigned short*)(ws + OFF_CBH);
    unsigned short* cbl = (unsigned short*)(ws + OFF_CBL);
    unsigned short* cbT = (unsigned short*)(ws + OFF_CBT);
    float* outA = ws + OFF_CBL;   // cbl reused after gemm1 (8MB)
    float* S    = ws + OFF_ZH;    // zh reused after gemm1 (512KB of 4MB)

    k_prep  <<<4097, 256, 0, stream>>>(z, cb, zh, zl, cbh, cbl, cbT, cnorm, accp);
    k_gemm1 <<<512, 512, 0, stream>>>(zh, zl, cbh, cbl, cnorm, var_q, logit);
    k_fused <<<1024, 512, 0, stream>>>(logit, accp);
    k_mid   <<<1024, 256, 0, stream>>>((const unsigned short*)logit, cbT, outA, out, S);
    k_tail2 <<<544, 256, 0, stream>>>(S, z, outA, out, accp);
    k_final <<<1, 64, 0, stream>>>(accp, var_q, out);
}